// Round 5
// baseline (450.619 us; speedup 1.0000x reference)
//
#include <hip/hip_runtime.h>

typedef unsigned short u16;
typedef __attribute__((ext_vector_type(8))) short short8;
typedef __attribute__((ext_vector_type(4))) float f32x4;

#define N_TOK 16384
#define DIN   1024
#define NE    16
#define DEMB  128
#define H1N   1024
#define H2N   512
#define DOUT  512
#define CAP   36864   // 32768 entries + 16*256 padding (256-aligned segments)
#define MT    (CAP/256)
#define RBLK  1024    // router blocks (16 tokens each)

// ---- workspace layout (bytes) ----
#define OFF_P      0ul           // 1024*16*4 = 65536
#define OFF_C      65536ul       // 16*4 (pad 256)
#define OFF_CTRL   65792ul       // counts[16]@0, poff[17]@128 (pad 256)
#define OFF_E01    66048ul       // 16384*2*4 = 131072
#define OFF_G01    197120ul      // 131072
#define OFF_GTOK   328192ul      // CAP*4 = 147456
#define OFF_GGATE  475648ul      // 147456
#define OFF_W1T    623104ul      // 16*1024*1024*2 = 33554432
#define OFF_XG     34177536ul    // CAP*1024*2 = 75497472
#define OFF_H1     109675008ul   // CAP*1024*2 = 75497472 (ends ~185.2 MB < proven 202)
// aliases (disjoint lifetimes, all on the serial stream):
#define OFF_BH     OFF_XG                 // bhist 65536 (dead before gather_x)
#define OFF_BB     (OFF_XG + 65536ul)     // bbase 65536
#define OFF_H2     OFF_XG                 // h2 = CAP*512*2 = 37748736 (xg dead after L1)
#define OFF_W2T    (OFF_XG + 41943040ul)  // W2T 16777216 (xg tail; conv after L1)
#define OFF_W3T    OFF_H1                 // W3T 8388608 (h1 dead after L2; conv after L2)

__device__ __forceinline__ u16 f2bf(float f) {
  union { float f; unsigned u; } v; v.f = f;
  unsigned r = v.u + 0x7fff + ((v.u >> 16) & 1);   // RNE, finite inputs
  return (u16)(r >> 16);
}

__device__ __forceinline__ void async_copy16(const u16* g, u16* l) {
  __builtin_amdgcn_global_load_lds((const __attribute__((address_space(1))) unsigned*)g,
                                   (__attribute__((address_space(3))) unsigned*)l,
                                   16, 0, 0);
}

// ---- K0: P = 2*Wr@emb^T [1024][16], c_e = 2*br.emb_e - |emb_e|^2 ----
__global__ void router_prep(const float* __restrict__ Wr, const float* __restrict__ br,
                            const float* __restrict__ emb, float* __restrict__ P,
                            float* __restrict__ c) {
  int idx = blockIdx.x * 256 + threadIdx.x;
  int row = idx >> 4, e = idx & 15;
  float s = 0.f;
  for (int j = 0; j < DEMB; ++j) s += Wr[row * DEMB + j] * emb[e * DEMB + j];
  P[row * NE + e] = 2.f * s;
  if (idx < NE) {
    float cc = 0.f, n2 = 0.f;
    for (int j = 0; j < DEMB; ++j) {
      float ev = emb[idx * DEMB + j];
      cc += br[j] * ev;
      n2 += ev * ev;
    }
    c[idx] = 2.f * cc - n2;
  }
}

// ---- K1: scores, top-2, gates; per-block LDS histogram -> bhist ----
__global__ void __launch_bounds__(256) router_score(
    const float* __restrict__ x, const float* __restrict__ P,
    const float* __restrict__ c, int* __restrict__ e01,
    float* __restrict__ g01, int* __restrict__ bhist) {
  __shared__ float xs[16384];
  __shared__ int lh[16];
  int wave = threadIdx.x >> 6, lane = threadIdx.x & 63;
  int e2 = lane & 7, kgl = lane >> 3;
  int tbase = blockIdx.x * 16 + wave * 4;
  float* xw = xs + wave * 4096;

  if (threadIdx.x < 16) lh[threadIdx.x] = 0;

  #pragma unroll
  for (int t = 0; t < 4; ++t) {
    const float* src = x + (size_t)(tbase + t) * DIN;
    #pragma unroll
    for (int q = 0; q < 4; ++q) {
      int g = q * 256 + lane * 4;
      *(float4*)(xw + t * 1024 + g) = *(const float4*)(src + g);
    }
  }
  __syncthreads();

  int te0 = 2 * e2, te1 = te0 + 1;
  float ce0 = c[te0], ce1 = c[te1];
  const float* Pb = P + te0;

  float acc0[4] = {0.f, 0.f, 0.f, 0.f};
  float acc1[4] = {0.f, 0.f, 0.f, 0.f};
  int cbase = kgl * 128;
  #pragma unroll 4
  for (int i = 0; i < 32; ++i) {
    int w = (kgl * 4 + i * 4) & 127;
    int idx = cbase + w;
    float2 pv0 = *(const float2*)(Pb + (size_t)(idx + 0) * NE);
    float2 pv1 = *(const float2*)(Pb + (size_t)(idx + 1) * NE);
    float2 pv2 = *(const float2*)(Pb + (size_t)(idx + 2) * NE);
    float2 pv3 = *(const float2*)(Pb + (size_t)(idx + 3) * NE);
    #pragma unroll
    for (int t = 0; t < 4; ++t) {
      float4 xv = *(const float4*)(xw + t * 1024 + idx);
      acc0[t] = fmaf(xv.x, pv0.x, acc0[t]); acc1[t] = fmaf(xv.x, pv0.y, acc1[t]);
      acc0[t] = fmaf(xv.y, pv1.x, acc0[t]); acc1[t] = fmaf(xv.y, pv1.y, acc1[t]);
      acc0[t] = fmaf(xv.z, pv2.x, acc0[t]); acc1[t] = fmaf(xv.z, pv2.y, acc1[t]);
      acc0[t] = fmaf(xv.w, pv3.x, acc0[t]); acc1[t] = fmaf(xv.w, pv3.y, acc1[t]);
    }
  }

  for (int t = 0; t < 4; ++t) {
    float s0 = acc0[t], s1 = acc1[t];
    #pragma unroll
    for (int off = 8; off <= 32; off <<= 1) {
      s0 += __shfl_xor(s0, off);
      s1 += __shfl_xor(s1, off);
    }
    s0 += ce0; s1 += ce1;
    float hi; int hidx;
    if (s0 >= s1) { hi = s0; hidx = te0; } else { hi = s1; hidx = te1; }
    float m1 = hi; int i1 = hidx;
    #pragma unroll
    for (int off = 1; off < 8; off <<= 1) {
      float so = __shfl_xor(m1, off); int io = __shfl_xor(i1, off);
      if (so > m1 || (so == m1 && io < i1)) { m1 = so; i1 = io; }
    }
    float c2; int c2i;
    if (i1 == te0)      { c2 = s1; c2i = te1; }
    else if (i1 == te1) { c2 = s0; c2i = te0; }
    else                { c2 = hi; c2i = hidx; }
    float m2 = c2; int i2 = c2i;
    #pragma unroll
    for (int off = 1; off < 8; off <<= 1) {
      float so = __shfl_xor(m2, off); int io = __shfl_xor(i2, off);
      if (so > m2 || (so == m2 && io < i2)) { m2 = so; i2 = io; }
    }
    if (lane == 0) {
      int tok = tbase + t;
      float ev = expf(m2 - m1);
      float inv = 1.f / (1.f + ev);
      e01[tok * 2 + 0] = i1; e01[tok * 2 + 1] = i2;
      g01[tok * 2 + 0] = inv; g01[tok * 2 + 1] = ev * inv;
      atomicAdd(&lh[i1], 1);
      atomicAdd(&lh[i2], 1);
    }
  }
  __syncthreads();
  if (threadIdx.x < 16) bhist[blockIdx.x * 16 + threadIdx.x] = lh[threadIdx.x];
}

// ---- K2: scan bhist -> counts, poff (256-aligned), per-block bases ----
__global__ void __launch_bounds__(1024) scan_offsets(
    const int* __restrict__ bhist, int* __restrict__ counts,
    int* __restrict__ poff, int* __restrict__ bbase) {
  int t = threadIdx.x;
  int e = t & 15, ch = t >> 4;
  int b0 = ch * 16;
  int s = 0;
  #pragma unroll
  for (int i = 0; i < 16; ++i) s += bhist[(b0 + i) * 16 + e];
  __shared__ int part[64][16];
  __shared__ int chbase[64][16];
  __shared__ int cnt[16];
  __shared__ int pof[16];
  part[ch][e] = s;
  __syncthreads();
  if (t < 16) {
    int run = 0;
    for (int c2 = 0; c2 < 64; ++c2) { chbase[c2][t] = run; run += part[c2][t]; }
    cnt[t] = run;
  }
  __syncthreads();
  if (t == 0) {
    int off = 0;
    for (int e2 = 0; e2 < NE; ++e2) {
      pof[e2] = off;
      poff[e2] = off;
      counts[e2] = cnt[e2];
      off += (cnt[e2] + 255) & ~255;
    }
    poff[NE] = off;
  }
  __syncthreads();
  int run = pof[e] + chbase[ch][e];
  #pragma unroll
  for (int i = 0; i < 16; ++i) {
    bbase[(b0 + i) * 16 + e] = run;
    run += bhist[(b0 + i) * 16 + e];
  }
}

// ---- K3: CSR entry lists ----
__global__ void build_lists(const int* __restrict__ e01, const float* __restrict__ g01,
                            const int* __restrict__ bbase, int* __restrict__ gtok,
                            float* __restrict__ ggate) {
  __shared__ int pos[16];
  int tid = threadIdx.x;
  if (tid < 16) pos[tid] = bbase[blockIdx.x * 16 + tid];
  __syncthreads();
  if (tid < 16) {
    int t = blockIdx.x * 16 + tid;
    #pragma unroll
    for (int k = 0; k < 2; ++k) {
      int e = e01[t * 2 + k];
      int p = atomicAdd(&pos[e], 1);
      gtok[p] = t;
      ggate[p] = g01[t * 2 + k];
    }
  }
}

// ---- K4: gather x rows -> bf16 (zeros in padding) ----
__global__ void gather_x(const float* __restrict__ x, const int* __restrict__ poff,
                         const int* __restrict__ counts, const int* __restrict__ gtok,
                         u16* __restrict__ xg) {
  int row = blockIdx.x * 4 + (threadIdx.x >> 6);
  int lane = threadIdx.x & 63;
  int total = poff[NE];
  bool valid = false; int t = 0;
  if (row < total) {
    int e = 0;
    while (row >= poff[e + 1]) ++e;
    if (row - poff[e] < counts[e]) { valid = true; t = gtok[row]; }
  }
  u16* dst = xg + (size_t)row * DIN + lane * 16;
  if (valid) {
    const float* src = x + (size_t)t * DIN + lane * 16;
    #pragma unroll
    for (int j = 0; j < 4; ++j) {
      float4 v = ((const float4*)src)[j];
      ushort4 o;
      o.x = f2bf(v.x); o.y = f2bf(v.y); o.z = f2bf(v.z); o.w = f2bf(v.w);
      ((ushort4*)dst)[j] = o;
    }
  } else {
    ushort4 z = {0, 0, 0, 0};
    #pragma unroll
    for (int j = 0; j < 4; ++j) ((ushort4*)dst)[j] = z;
  }
}

// ---- K5: weight convert+transpose: [E][K][N] f32 -> [E][N][K] bf16 ----
template<int K, int N>
__global__ void conv_w(const float* __restrict__ W, u16* __restrict__ WT) {
  __shared__ float tile[64][65];
  int e = blockIdx.z;
  int n0 = blockIdx.x * 64, k0 = blockIdx.y * 64;
  int tx = threadIdx.x & 63, ty = threadIdx.x >> 6;
  const float* Wb = W + (size_t)e * K * N;
  #pragma unroll
  for (int p = 0; p < 16; ++p) {
    int k = p * 4 + ty;
    tile[k][tx] = Wb[(size_t)(k0 + k) * N + n0 + tx];
  }
  __syncthreads();
  u16* WTb = WT + (size_t)e * N * K;
  #pragma unroll
  for (int p = 0; p < 16; ++p) {
    int n = p * 4 + ty;
    WTb[(size_t)(n0 + n) * K + k0 + tx] = f2bf(tile[tx][n]);
  }
}

// ======== 8-phase 256x256 MoE GEMM (T1+T2+T3+T4+T5) ========
// A[rows][K] bf16, B_e[N][K] bf16 (both K-contig). BK=64, 8 waves, 128 KiB LDS.
// Phases = block C-quadrants: ph1(Mlo,Nlo) ph2(Mlo,Nhi) ph3(Mhi,Nhi) ph4(Mhi,Nlo).
// Stage order (next tile, other buffer): ph1->Alo' ph2->Blo' ph3->Bhi' ph4->Ahi'.
// vmcnt(6) before barrier in ph1-3 (3 half-tiles/6 loads stay in flight); ph4: none.
// LDS swizzle: chunk c (16B) of row r stored at slot c^(r&7) via pre-swizzled source;
// ds_read applies the same XOR -> 2 lanes/bank (free, verified 0-conflict in r4).
#define WAITBAR asm volatile("s_waitcnt vmcnt(6)\n\ts_barrier" ::: "memory")

#define LOAD_A(BASE, OFF) { _Pragma("unroll") for (int m = 0; m < 4; ++m) { \
    const u16* p_ = (BASE) + ((OFF) + qm * 64 + m * 16 + fr) * 64; \
    a[m][0] = *(const short8*)(p_ + cx0); a[m][1] = *(const short8*)(p_ + cx1); } }

#define LOAD_B(BASE, OFF, BF) { _Pragma("unroll") for (int n = 0; n < 2; ++n) { \
    const u16* p_ = (BASE) + ((OFF) + qn * 32 + n * 16 + fr) * 64; \
    BF[n][0] = *(const short8*)(p_ + cx0); BF[n][1] = *(const short8*)(p_ + cx1); } }

#define DO_MFMA(ACC, BF) { __builtin_amdgcn_s_setprio(1); \
  _Pragma("unroll") for (int m = 0; m < 4; ++m) \
  _Pragma("unroll") for (int n = 0; n < 2; ++n) { \
    ACC[m][n] = __builtin_amdgcn_mfma_f32_16x16x32_bf16(a[m][0], BF[n][0], ACC[m][n], 0, 0, 0); \
    ACC[m][n] = __builtin_amdgcn_mfma_f32_16x16x32_bf16(a[m][1], BF[n][1], ACC[m][n], 0, 0, 0); } \
  __builtin_amdgcn_s_setprio(0); }

#define EPI0(ACC, RO, CO) { _Pragma("unroll") for (int m = 0; m < 4; ++m) { \
    int gr0 = gr_base + (RO) + m * 16; \
    _Pragma("unroll") for (int n = 0; n < 2; ++n) { \
      int gc = gc_base + (CO) + n * 16; \
      float bvs = be[gc]; \
      _Pragma("unroll") for (int r = 0; r < 4; ++r) { \
        float v = ACC[m][n][r] + bvs; v = v > 0.f ? v : 0.f; \
        Cb[(size_t)(gr0 + r) * N + gc] = f2bf(v); } } } }

#define EPI1(ACC, RO, CO) { _Pragma("unroll") for (int m = 0; m < 4; ++m) { \
    int gr0 = gr_base + (RO) + m * 16; \
    _Pragma("unroll") for (int r = 0; r < 4; ++r) { \
      int gr = gr0 + r; \
      if ((gr - poe) < ce) { \
        int tk = gtok[gr]; float gt = ggate[gr]; \
        _Pragma("unroll") for (int n = 0; n < 2; ++n) { \
          int gc = gc_base + (CO) + n * 16; \
          float v = (ACC[m][n][r] + be[gc]) * gt; \
          atomicAdd(outF + (size_t)tk * N + gc, v); } } } } }

template<int MODE>
__global__ void __launch_bounds__(512, 2)
gemm_moe256(const u16* __restrict__ A, const u16* __restrict__ Ball,
            const float* __restrict__ bias, u16* __restrict__ Cb,
            float* __restrict__ outF,
            const int* __restrict__ poff, const int* __restrict__ counts,
            const int* __restrict__ gtok, const float* __restrict__ ggate,
            int K, int N, int nblk) {
  __shared__ u16 As[2][16384];
  __shared__ u16 Bs[2][16384];

  // T1: bijective XCD remap, nb-fastest
  int bid = blockIdx.x;
  int q8 = nblk >> 3, r8 = nblk & 7;
  int xcd = bid & 7, sidx = bid >> 3;
  int wg = (xcd < r8 ? xcd * (q8 + 1) : r8 * (q8 + 1) + (xcd - r8) * q8) + sidx;
  int NB = N >> 8;
  int rb = wg / NB, nb = wg - rb * NB;
  int row_base = rb * 256;
  if (row_base >= poff[NE]) return;
  int e = 0;
  while (row_base >= poff[e + 1]) ++e;

  int tid = threadIdx.x;
  int lane = tid & 63, wv = tid >> 6;
  int qm = wv >> 2, qn = wv & 3;          // wave's 64x32 sub-block within each quadrant
  int fr = lane & 15, kq = lane >> 4;
  int n_base = nb * 256;

  const u16* gA = A + (size_t)row_base * K;
  const u16* gB = Ball + (size_t)e * N * K + (size_t)n_base * K;

  int srow = tid >> 3;
  int swz_s = ((tid & 7) ^ (srow & 7)) * 8;     // pre-swizzled source chunk (u16)
  int cx0 = (kq ^ (fr & 7)) * 8;                // ds_read chunk XOR, ks=0
  int cx1 = ((kq ^ 4) ^ (fr & 7)) * 8;          // ks=1

  u16* Ab = &As[0][0];
  u16* Bb = &Bs[0][0];

  auto stage = [&](int buf, int half, const u16* g, u16* lb, int kt) {
    u16* l = lb + buf * 16384 + half * 8192 + tid * 8;
    int r0 = half * 128 + srow;
    async_copy16(g + (size_t)r0 * K + kt + swz_s, l);
    async_copy16(g + (size_t)(r0 + 64) * K + kt + swz_s, l + 4096);
  };

  short8 a[4][2], blo[2][2], bhi[2][2];
  f32x4 c00[4][2], c01[4][2], c11[4][2], c10[4][2];
  #pragma unroll
  for (int m = 0; m < 4; ++m)
    #pragma unroll
    for (int n = 0; n < 2; ++n) {
      c00[m][n] = (f32x4){0.f, 0.f, 0.f, 0.f};
      c01[m][n] = (f32x4){0.f, 0.f, 0.f, 0.f};
      c11[m][n] = (f32x4){0.f, 0.f, 0.f, 0.f};
      c10[m][n] = (f32x4){0.f, 0.f, 0.f, 0.f};
    }

  // prologue: tile 0, order [Alo, Blo, Bhi, Ahi]
  stage(0, 0, gA, Ab, 0);
  stage(0, 0, gB, Bb, 0);
  stage(0, 1, gB, Bb, 0);
  stage(0, 1, gA, Ab, 0);

  int NT = K >> 6;
  for (int t = 0; t < NT; ++t) {
    int cur = t & 1, nxt = cur ^ 1;
    int ktn = (t + 1 < NT ? (t + 1) : t) << 6;   // clamp: restage last tile (unused)
    const u16* Ac = Ab + cur * 16384;
    const u16* Bc = Bb + cur * 16384;
    // phase 1: (Mlo, Nlo)
    stage(nxt, 0, gA, Ab, ktn);                  // Alo'
    WAITBAR;
    LOAD_A(Ac, 0);
    LOAD_B(Bc, 0, blo);
    DO_MFMA(c00, blo);
    // phase 2: (Mlo, Nhi)
    stage(nxt, 0, gB, Bb, ktn);                  // Blo'
    WAITBAR;
    LOAD_B(Bc, 128, bhi);
    DO_MFMA(c01, bhi);
    // phase 3: (Mhi, Nhi)
    stage(nxt, 1, gB, Bb, ktn);                  // Bhi'
    WAITBAR;
    LOAD_A(Ac, 128);
    DO_MFMA(c11, bhi);
    // phase 4: (Mhi, Nlo) — no ds_read, no barrier
    stage(nxt, 1, gA, Ab, ktn);                  // Ahi'
    DO_MFMA(c10, blo);
  }

  const float* be = bias + (size_t)e * N;
  int gr_base = row_base + qm * 64 + kq * 4;     // C/D: col=lane&15, row=kq*4+reg
  int gc_base = n_base + qn * 32 + fr;
  if constexpr (MODE == 0) {
    EPI0(c00, 0, 0); EPI0(c01, 0, 128); EPI0(c11, 128, 128); EPI0(c10, 128, 0);
  } else {
    int poe = poff[e], ce = counts[e];
    EPI1(c00, 0, 0); EPI1(c01, 0, 128); EPI1(c11, 128, 128); EPI1(c10, 128, 0);
  }
}

extern "C" void kernel_launch(void* const* d_in, const int* in_sizes, int n_in,
                              void* d_out, int out_size, void* d_ws, size_t ws_size,
                              hipStream_t stream) {
  const float* x   = (const float*)d_in[0];
  const float* Wr  = (const float*)d_in[1];
  const float* br  = (const float*)d_in[2];
  const float* emb = (const float*)d_in[3];
  const float* W1  = (const float*)d_in[4];
  const float* b1  = (const float*)d_in[5];
  const float* W2  = (const float*)d_in[6];
  const float* b2  = (const float*)d_in[7];
  const float* W3  = (const float*)d_in[8];
  const float* b3  = (const float*)d_in[9];
  float* out = (float*)d_out;
  char* ws = (char*)d_ws;

  float* P      = (float*)(ws + OFF_P);
  float* c      = (float*)(ws + OFF_C);
  int*   counts = (int*)(ws + OFF_CTRL);
  int*   poff   = (int*)(ws + OFF_CTRL + 128);
  int*   e01    = (int*)(ws + OFF_E01);
  float* g01    = (float*)(ws + OFF_G01);
  int*   gtok   = (int*)(ws + OFF_GTOK);
  float* ggate  = (float*)(ws + OFF_GGATE);
  int*   bhist  = (int*)(ws + OFF_BH);
  int*   bbase  = (int*)(ws + OFF_BB);
  u16*   W1T    = (u16*)(ws + OFF_W1T);
  u16*   W2T    = (u16*)(ws + OFF_W2T);
  u16*   W3T    = (u16*)(ws + OFF_W3T);
  u16*   xg     = (u16*)(ws + OFF_XG);
  u16*   h1     = (u16*)(ws + OFF_H1);
  u16*   h2     = (u16*)(ws + OFF_H2);

  hipMemsetAsync(d_out, 0, (size_t)N_TOK * DOUT * sizeof(float), stream);

  router_prep<<<64, 256, 0, stream>>>(Wr, br, emb, P, c);
  router_score<<<RBLK, 256, 0, stream>>>(x, P, c, e01, g01, bhist);
  scan_offsets<<<1, 1024, 0, stream>>>(bhist, counts, poff, bbase);
  build_lists<<<RBLK, 64, 0, stream>>>(e01, g01, bbase, gtok, ggate);
  gather_x<<<CAP / 4, 256, 0, stream>>>(x, poff, counts, gtok, xg);

  int nb1 = (H1N >> 8) * MT;   // 4*144 = 576
  int nb2 = (H2N >> 8) * MT;   // 2*144 = 288
  int nb3 = (DOUT >> 8) * MT;  // 2*144 = 288

  conv_w<DIN, H1N><<<dim3(H1N / 64, DIN / 64, NE), 256, 0, stream>>>(W1, W1T);
  gemm_moe256<0><<<nb1, 512, 0, stream>>>(xg, W1T, b1, h1, nullptr,
                                          poff, counts, nullptr, nullptr, DIN, H1N, nb1);
  conv_w<H1N, H2N><<<dim3(H2N / 64, H1N / 64, NE), 256, 0, stream>>>(W2, W2T);
  gemm_moe256<0><<<nb2, 512, 0, stream>>>(h1, W2T, b2, h2, nullptr,
                                          poff, counts, nullptr, nullptr, H1N, H2N, nb2);
  conv_w<H2N, DOUT><<<dim3(DOUT / 64, H2N / 64, NE), 256, 0, stream>>>(W3, W3T);
  gemm_moe256<1><<<nb3, 512, 0, stream>>>(h2, W3T, b3, nullptr, out,
                                          poff, counts, gtok, ggate, H2N, DOUT, nb3);
}

// Round 6
// 381.852 us; speedup vs baseline: 1.1801x; 1.1801x over previous
//
#include <hip/hip_runtime.h>

typedef unsigned short u16;
typedef __attribute__((ext_vector_type(8))) short short8;
typedef __attribute__((ext_vector_type(4))) float f32x4;

#define N_TOK 16384
#define DIN   1024
#define NE    16
#define DEMB  128
#define H1N   1024
#define H2N   512
#define DOUT  512
#define CAP   34816   // 32768 entries + 16*128 padding
#define MT    (CAP/128)
#define RBLK  1024    // router blocks (16 tokens each)

// ---- workspace layout (bytes) ----
#define OFF_P      0ul          // 1024*16*4 = 65536
#define OFF_C      65536ul      // 16*4 (pad 256)
#define OFF_CTRL   65792ul      // counts[16]@0, poff[17]@128 (pad 256)
#define OFF_E01    66048ul      // 16384*2*4 = 131072
#define OFF_G01    197120ul     // 131072
#define OFF_GTOK   328192ul     // CAP*4 = 139264
#define OFF_GGATE  467456ul     // 139264
#define OFF_W1T    606720ul     // 16*1024*1024*2 = 33554432
#define OFF_W2T    34161152ul   // 16*512*1024*2 = 16777216
#define OFF_W3T    50938368ul   // 16*512*512*2  = 8388608
#define OFF_XG     59326976ul   // CAP*1024*2 = 71303168
#define OFF_H1     130630144ul  // CAP*1024*2 = 71303168  (ends ~202 MB)
#define OFF_H2     OFF_XG       // h2 aliases xg (disjoint lifetimes)
// bhist/bbase alias head of xg: dead before gather_x writes xg
#define OFF_BH     OFF_XG              // 1024*16*4 = 65536
#define OFF_BB     (OFF_XG + 65536ul)  // 65536

__device__ __forceinline__ u16 f2bf(float f) {
  union { float f; unsigned u; } v; v.f = f;
  unsigned r = v.u + 0x7fff + ((v.u >> 16) & 1);   // RNE, finite inputs
  return (u16)(r >> 16);
}

__device__ __forceinline__ void async_copy16(const u16* g, u16* l) {
  __builtin_amdgcn_global_load_lds((const __attribute__((address_space(1))) unsigned*)g,
                                   (__attribute__((address_space(3))) unsigned*)l,
                                   16, 0, 0);
}

// ---- K0: P = 2*Wr@emb^T [1024][16], c_e = 2*br.emb_e - |emb_e|^2 ----
__global__ void router_prep(const float* __restrict__ Wr, const float* __restrict__ br,
                            const float* __restrict__ emb, float* __restrict__ P,
                            float* __restrict__ c) {
  int idx = blockIdx.x * 256 + threadIdx.x;
  int row = idx >> 4, e = idx & 15;
  float s = 0.f;
  for (int j = 0; j < DEMB; ++j) s += Wr[row * DEMB + j] * emb[e * DEMB + j];
  P[row * NE + e] = 2.f * s;
  if (idx < NE) {
    float cc = 0.f, n2 = 0.f;
    for (int j = 0; j < DEMB; ++j) {
      float ev = emb[idx * DEMB + j];
      cc += br[j] * ev;
      n2 += ev * ev;
    }
    c[idx] = 2.f * cc - n2;
  }
}

// ---- K1: scores, top-2, gates; per-block LDS histogram -> bhist ----
__global__ void __launch_bounds__(256) router_score(
    const float* __restrict__ x, const float* __restrict__ P,
    const float* __restrict__ c, int* __restrict__ e01,
    float* __restrict__ g01, int* __restrict__ bhist) {
  __shared__ float xs[16384];
  __shared__ int lh[16];
  int wave = threadIdx.x >> 6, lane = threadIdx.x & 63;
  int e2 = lane & 7, kgl = lane >> 3;
  int tbase = blockIdx.x * 16 + wave * 4;
  float* xw = xs + wave * 4096;

  if (threadIdx.x < 16) lh[threadIdx.x] = 0;

  #pragma unroll
  for (int t = 0; t < 4; ++t) {
    const float* src = x + (size_t)(tbase + t) * DIN;
    #pragma unroll
    for (int q = 0; q < 4; ++q) {
      int g = q * 256 + lane * 4;
      *(float4*)(xw + t * 1024 + g) = *(const float4*)(src + g);
    }
  }
  __syncthreads();

  int te0 = 2 * e2, te1 = te0 + 1;
  float ce0 = c[te0], ce1 = c[te1];
  const float* Pb = P + te0;

  float acc0[4] = {0.f, 0.f, 0.f, 0.f};
  float acc1[4] = {0.f, 0.f, 0.f, 0.f};
  int cbase = kgl * 128;
  #pragma unroll 4
  for (int i = 0; i < 32; ++i) {
    int w = (kgl * 4 + i * 4) & 127;
    int idx = cbase + w;
    float2 pv0 = *(const float2*)(Pb + (size_t)(idx + 0) * NE);
    float2 pv1 = *(const float2*)(Pb + (size_t)(idx + 1) * NE);
    float2 pv2 = *(const float2*)(Pb + (size_t)(idx + 2) * NE);
    float2 pv3 = *(const float2*)(Pb + (size_t)(idx + 3) * NE);
    #pragma unroll
    for (int t = 0; t < 4; ++t) {
      float4 xv = *(const float4*)(xw + t * 1024 + idx);
      acc0[t] = fmaf(xv.x, pv0.x, acc0[t]); acc1[t] = fmaf(xv.x, pv0.y, acc1[t]);
      acc0[t] = fmaf(xv.y, pv1.x, acc0[t]); acc1[t] = fmaf(xv.y, pv1.y, acc1[t]);
      acc0[t] = fmaf(xv.z, pv2.x, acc0[t]); acc1[t] = fmaf(xv.z, pv2.y, acc1[t]);
      acc0[t] = fmaf(xv.w, pv3.x, acc0[t]); acc1[t] = fmaf(xv.w, pv3.y, acc1[t]);
    }
  }

  for (int t = 0; t < 4; ++t) {
    float s0 = acc0[t], s1 = acc1[t];
    #pragma unroll
    for (int off = 8; off <= 32; off <<= 1) {
      s0 += __shfl_xor(s0, off);
      s1 += __shfl_xor(s1, off);
    }
    s0 += ce0; s1 += ce1;
    float hi; int hidx;
    if (s0 >= s1) { hi = s0; hidx = te0; } else { hi = s1; hidx = te1; }
    float m1 = hi; int i1 = hidx;
    #pragma unroll
    for (int off = 1; off < 8; off <<= 1) {
      float so = __shfl_xor(m1, off); int io = __shfl_xor(i1, off);
      if (so > m1 || (so == m1 && io < i1)) { m1 = so; i1 = io; }
    }
    float c2; int c2i;
    if (i1 == te0)      { c2 = s1; c2i = te1; }
    else if (i1 == te1) { c2 = s0; c2i = te0; }
    else                { c2 = hi; c2i = hidx; }
    float m2 = c2; int i2 = c2i;
    #pragma unroll
    for (int off = 1; off < 8; off <<= 1) {
      float so = __shfl_xor(m2, off); int io = __shfl_xor(i2, off);
      if (so > m2 || (so == m2 && io < i2)) { m2 = so; i2 = io; }
    }
    if (lane == 0) {
      int tok = tbase + t;
      float ev = expf(m2 - m1);
      float inv = 1.f / (1.f + ev);
      e01[tok * 2 + 0] = i1; e01[tok * 2 + 1] = i2;
      g01[tok * 2 + 0] = inv; g01[tok * 2 + 1] = ev * inv;
      atomicAdd(&lh[i1], 1);
      atomicAdd(&lh[i2], 1);
    }
  }
  __syncthreads();
  if (threadIdx.x < 16) bhist[blockIdx.x * 16 + threadIdx.x] = lh[threadIdx.x];
}

// ---- K2: scan bhist -> counts, poff, per-block bases ----
__global__ void __launch_bounds__(1024) scan_offsets(
    const int* __restrict__ bhist, int* __restrict__ counts,
    int* __restrict__ poff, int* __restrict__ bbase) {
  int t = threadIdx.x;
  int e = t & 15, ch = t >> 4;
  int b0 = ch * 16;
  int s = 0;
  #pragma unroll
  for (int i = 0; i < 16; ++i) s += bhist[(b0 + i) * 16 + e];
  __shared__ int part[64][16];
  __shared__ int chbase[64][16];
  __shared__ int cnt[16];
  __shared__ int pof[16];
  part[ch][e] = s;
  __syncthreads();
  if (t < 16) {
    int run = 0;
    for (int c2 = 0; c2 < 64; ++c2) { chbase[c2][t] = run; run += part[c2][t]; }
    cnt[t] = run;
  }
  __syncthreads();
  if (t == 0) {
    int off = 0;
    for (int e2 = 0; e2 < NE; ++e2) {
      pof[e2] = off;
      poff[e2] = off;
      counts[e2] = cnt[e2];
      off += (cnt[e2] + 127) & ~127;
    }
    poff[NE] = off;
  }
  __syncthreads();
  int run = pof[e] + chbase[ch][e];
  #pragma unroll
  for (int i = 0; i < 16; ++i) {
    bbase[(b0 + i) * 16 + e] = run;
    run += bhist[(b0 + i) * 16 + e];
  }
}

// ---- K3: CSR entry lists ----
__global__ void build_lists(const int* __restrict__ e01, const float* __restrict__ g01,
                            const int* __restrict__ bbase, int* __restrict__ gtok,
                            float* __restrict__ ggate) {
  __shared__ int pos[16];
  int tid = threadIdx.x;
  if (tid < 16) pos[tid] = bbase[blockIdx.x * 16 + tid];
  __syncthreads();
  if (tid < 16) {
    int t = blockIdx.x * 16 + tid;
    #pragma unroll
    for (int k = 0; k < 2; ++k) {
      int e = e01[t * 2 + k];
      int p = atomicAdd(&pos[e], 1);
      gtok[p] = t;
      ggate[p] = g01[t * 2 + k];
    }
  }
}

// ---- K4: gather x rows -> bf16 (zeros in padding) ----
__global__ void gather_x(const float* __restrict__ x, const int* __restrict__ poff,
                         const int* __restrict__ counts, const int* __restrict__ gtok,
                         u16* __restrict__ xg) {
  int row = blockIdx.x * 4 + (threadIdx.x >> 6);
  int lane = threadIdx.x & 63;
  int total = poff[NE];
  bool valid = false; int t = 0;
  if (row < total) {
    int e = 0;
    while (row >= poff[e + 1]) ++e;
    if (row - poff[e] < counts[e]) { valid = true; t = gtok[row]; }
  }
  u16* dst = xg + (size_t)row * DIN + lane * 16;
  if (valid) {
    const float* src = x + (size_t)t * DIN + lane * 16;
    #pragma unroll
    for (int j = 0; j < 4; ++j) {
      float4 v = ((const float4*)src)[j];
      ushort4 o;
      o.x = f2bf(v.x); o.y = f2bf(v.y); o.z = f2bf(v.z); o.w = f2bf(v.w);
      ((ushort4*)dst)[j] = o;
    }
  } else {
    ushort4 z = {0, 0, 0, 0};
    #pragma unroll
    for (int j = 0; j < 4; ++j) ((ushort4*)dst)[j] = z;
  }
}

// ---- K5: weight convert+transpose: [E][K][N] f32 -> [E][N][K] bf16 ----
template<int K, int N>
__global__ void conv_w(const float* __restrict__ W, u16* __restrict__ WT) {
  __shared__ float tile[64][65];
  int e = blockIdx.z;
  int n0 = blockIdx.x * 64, k0 = blockIdx.y * 64;
  int tx = threadIdx.x & 63, ty = threadIdx.x >> 6;
  const float* Wb = W + (size_t)e * K * N;
  #pragma unroll
  for (int p = 0; p < 16; ++p) {
    int k = p * 4 + ty;
    tile[k][tx] = Wb[(size_t)(k0 + k) * N + n0 + tx];
  }
  __syncthreads();
  u16* WTb = WT + (size_t)e * N * K;
  #pragma unroll
  for (int p = 0; p < 16; ++p) {
    int n = p * 4 + ty;
    WTb[(size_t)(n0 + n) * K + k0 + tx] = f2bf(tile[tx][n]);
  }
}

// ---- GEMM: A[rows][K] bf16 x B_e[N][K] bf16 (K-contig both) ----
// r4-proven structure + T3-minimum double-buffer: stage tile t+1 into buf[cur^1]
// BEFORE ds_read+MFMA of buf[cur]; one __syncthreads (vmcnt0+lgkm0+barrier) per
// K-step. Write nxt || read cur are disjoint; barrier separates buffer flips.
// T1 bijective XCD remap + source-permuted LDS swizzle (0 conflicts, r4-verified).
// MODE 0: Cb = bf16(relu(acc+bias)); MODE 1: atomicAdd(out[token], gate*(acc+bias))
template<int MODE>
__global__ void __launch_bounds__(256)
gemm_moe(const u16* __restrict__ A, const u16* __restrict__ Ball,
         const float* __restrict__ bias, u16* __restrict__ Cb, float* __restrict__ outF,
         const int* __restrict__ poff, const int* __restrict__ counts,
         const int* __restrict__ gtok, const float* __restrict__ ggate,
         int K, int N, int nblk) {
  __shared__ u16 Asm[2][4096];
  __shared__ u16 Bsm[2][4096];

  // bijective XCD remap (m204): consecutive wg land on the same XCD chunk
  int bid = blockIdx.x;
  int q = nblk >> 3, r = nblk & 7;
  int xcd = bid & 7, sidx = bid >> 3;
  int wg = (xcd < r ? xcd * (q + 1) : r * (q + 1) + (xcd - r) * q) + sidx;
  int NB = N >> 7;
  int rb = wg / NB, nb = wg - rb * NB;   // nb fastest: same A-tile contiguous on one XCD

  int row_base = rb * 128;
  if (row_base >= poff[NE]) return;
  int e = 0;
  while (row_base >= poff[e + 1]) ++e;

  int tid = threadIdx.x;
  int wave = tid >> 6, lane = tid & 63;
  int wm = wave >> 1, wn = wave & 1;
  int fr = lane & 15, kq = lane >> 4;
  int n_base = nb * 128;

  const u16* Arow = A + (size_t)row_base * K;
  const u16* Brow = Ball + (size_t)e * N * K + (size_t)n_base * K;

  f32x4 acc[4][4];
  #pragma unroll
  for (int m = 0; m < 4; ++m)
    #pragma unroll
    for (int n = 0; n < 4; ++n)
      acc[m][n] = (f32x4){0.f, 0.f, 0.f, 0.f};

  int swz = (fr >> 1) & 3;                 // = (row>>1)&3 for all fragment rows

  auto stage_tile = [&](int buf, int kt) {
    #pragma unroll
    for (int j = 0; j < 2; ++j) {
      int lin = j * 256 + tid;
      int rr = lin >> 2, cc = lin & 3;
      int ch = cc ^ ((rr >> 1) & 3);       // source chunk permutation (involution pair)
      async_copy16(Arow + (size_t)rr * K + kt + ch * 8, &Asm[buf][lin * 8]);
      async_copy16(Brow + (size_t)rr * K + kt + ch * 8, &Bsm[buf][lin * 8]);
    }
  };

  // prologue: tile 0 into buf 0
  stage_tile(0, 0);
  __syncthreads();

  int nstep = K >> 5;
  int cur = 0;
  for (int s = 0; s < nstep; ++s) {
    if (s + 1 < nstep) stage_tile(cur ^ 1, (s + 1) << 5);   // overlap with MFMA below
    short8 av[4], bv[4];
    #pragma unroll
    for (int m = 0; m < 4; ++m)
      av[m] = *(const short8*)(&Asm[cur][((wm * 64 + m * 16 + fr) * 4 + (kq ^ swz)) * 8]);
    #pragma unroll
    for (int n = 0; n < 4; ++n)
      bv[n] = *(const short8*)(&Bsm[cur][((wn * 64 + n * 16 + fr) * 4 + (kq ^ swz)) * 8]);
    #pragma unroll
    for (int m = 0; m < 4; ++m)
      #pragma unroll
      for (int n = 0; n < 4; ++n)
        acc[m][n] = __builtin_amdgcn_mfma_f32_16x16x32_bf16(av[m], bv[n], acc[m][n], 0, 0, 0);
    __syncthreads();                       // drain stage loads + all reads of cur done
    cur ^= 1;
  }

  int crow = (lane >> 4) * 4;   // C/D: col=lane&15, row=(lane>>4)*4+reg
  int ccol = lane & 15;
  const float* be = bias + (size_t)e * N;
  if constexpr (MODE == 0) {
    #pragma unroll
    for (int m = 0; m < 4; ++m) {
      int gr0 = row_base + wm * 64 + m * 16 + crow;
      #pragma unroll
      for (int n = 0; n < 4; ++n) {
        int gc = n_base + wn * 64 + n * 16 + ccol;
        float bvs = be[gc];
        #pragma unroll
        for (int r2 = 0; r2 < 4; ++r2) {
          float v = acc[m][n][r2] + bvs;
          v = v > 0.f ? v : 0.f;
          Cb[(size_t)(gr0 + r2) * N + gc] = f2bf(v);
        }
      }
    }
  } else {
    int poe = poff[e], ce = counts[e];
    #pragma unroll
    for (int m = 0; m < 4; ++m) {
      int gr0 = row_base + wm * 64 + m * 16 + crow;
      int tk[4]; float gt[4]; bool vl[4];
      #pragma unroll
      for (int r2 = 0; r2 < 4; ++r2) {
        int gr = gr0 + r2;
        vl[r2] = (gr - poe) < ce;
        tk[r2] = vl[r2] ? gtok[gr] : 0;
        gt[r2] = vl[r2] ? ggate[gr] : 0.f;
      }
      #pragma unroll
      for (int n = 0; n < 4; ++n) {
        int gc = n_base + wn * 64 + n * 16 + ccol;
        float bvs = be[gc];
        #pragma unroll
        for (int r2 = 0; r2 < 4; ++r2) {
          if (vl[r2]) {
            float v = (acc[m][n][r2] + bvs) * gt[r2];
            atomicAdd(outF + (size_t)tk[r2] * N + gc, v);
          }
        }
      }
    }
  }
}

extern "C" void kernel_launch(void* const* d_in, const int* in_sizes, int n_in,
                              void* d_out, int out_size, void* d_ws, size_t ws_size,
                              hipStream_t stream) {
  const float* x   = (const float*)d_in[0];
  const float* Wr  = (const float*)d_in[1];
  const float* br  = (const float*)d_in[2];
  const float* emb = (const float*)d_in[3];
  const float* W1  = (const float*)d_in[4];
  const float* b1  = (const float*)d_in[5];
  const float* W2  = (const float*)d_in[6];
  const float* b2  = (const float*)d_in[7];
  const float* W3  = (const float*)d_in[8];
  const float* b3  = (const float*)d_in[9];
  float* out = (float*)d_out;
  char* ws = (char*)d_ws;

  float* P      = (float*)(ws + OFF_P);
  float* c      = (float*)(ws + OFF_C);
  int*   counts = (int*)(ws + OFF_CTRL);
  int*   poff   = (int*)(ws + OFF_CTRL + 128);
  int*   e01    = (int*)(ws + OFF_E01);
  float* g01    = (float*)(ws + OFF_G01);
  int*   gtok   = (int*)(ws + OFF_GTOK);
  float* ggate  = (float*)(ws + OFF_GGATE);
  int*   bhist  = (int*)(ws + OFF_BH);
  int*   bbase  = (int*)(ws + OFF_BB);
  u16*   W1T    = (u16*)(ws + OFF_W1T);
  u16*   W2T    = (u16*)(ws + OFF_W2T);
  u16*   W3T    = (u16*)(ws + OFF_W3T);
  u16*   xg     = (u16*)(ws + OFF_XG);
  u16*   h1     = (u16*)(ws + OFF_H1);
  u16*   h2     = (u16*)(ws + OFF_H2);

  hipMemsetAsync(d_out, 0, (size_t)N_TOK * DOUT * sizeof(float), stream);

  conv_w<DIN, H1N><<<dim3(H1N / 64, DIN / 64, NE), 256, 0, stream>>>(W1, W1T);
  conv_w<H1N, H2N><<<dim3(H2N / 64, H1N / 64, NE), 256, 0, stream>>>(W2, W2T);
  conv_w<H2N, DOUT><<<dim3(DOUT / 64, H2N / 64, NE), 256, 0, stream>>>(W3, W3T);

  router_prep<<<64, 256, 0, stream>>>(Wr, br, emb, P, c);
  router_score<<<RBLK, 256, 0, stream>>>(x, P, c, e01, g01, bhist);
  scan_offsets<<<1, 1024, 0, stream>>>(bhist, counts, poff, bbase);
  build_lists<<<RBLK, 64, 0, stream>>>(e01, g01, bbase, gtok, ggate);
  gather_x<<<CAP / 4, 256, 0, stream>>>(x, poff, counts, gtok, xg);

  int nb1 = (H1N / 128) * MT;
  int nb2 = (H2N / 128) * MT;
  int nb3 = (DOUT / 128) * MT;
  gemm_moe<0><<<nb1, 256, 0, stream>>>(xg, W1T, b1, h1, nullptr,
                                       poff, counts, nullptr, nullptr, DIN, H1N, nb1);
  gemm_moe<0><<<nb2, 256, 0, stream>>>(h1, W2T, b2, h2, nullptr,
                                       poff, counts, nullptr, nullptr, H1N, H2N, nb2);
  gemm_moe<1><<<nb3, 256, 0, stream>>>(h2, W3T, b3, nullptr, out,
                                       poff, counts, gtok, ggate, H2N, DOUT, nb3);
}

// Round 7
// 343.104 us; speedup vs baseline: 1.3134x; 1.1129x over previous
//
#include <hip/hip_runtime.h>

typedef unsigned short u16;
typedef __attribute__((ext_vector_type(8))) short short8;
typedef __attribute__((ext_vector_type(4))) float f32x4;

#define N_TOK 16384
#define DIN   1024
#define NE    16
#define DEMB  128
#define H1N   1024
#define H2N   512
#define DOUT  512
#define CAP   34816   // 32768 entries + 16*128 padding
#define MT    (CAP/128)
#define RBLK  1024    // router blocks (16 tokens each)

// ---- workspace layout (bytes), alias-free, ends 199,967,232 (< proven 201.9 MB) ----
#define OFF_P      0ul           // 65536
#define OFF_C      65536ul       // 256
#define OFF_CTRL   65792ul       // counts[16]@0, poff[17]@128 (256)
#define OFF_E01    66048ul       // 131072
#define OFF_G01    197120ul      // 131072
#define OFF_GTOK   328192ul      // CAP*4 = 139264
#define OFF_GGATE  467456ul      // 139264
#define OFF_BH     606720ul      // 65536
#define OFF_BB     672256ul      // 65536
#define OFF_W1T    737792ul      // 33554432
#define OFF_W2T    34292224ul    // 16777216
#define OFF_W3T    51069440ul    // 8388608
#define OFF_XBF    59458048ul    // N_TOK*1024*2 = 33554432
#define OFF_H1     93012480ul    // CAP*1024*2 = 71303168
#define OFF_H2     164315648ul   // CAP*512*2  = 35651584

__device__ __forceinline__ u16 f2bf(float f) {
  union { float f; unsigned u; } v; v.f = f;
  unsigned r = v.u + 0x7fff + ((v.u >> 16) & 1);   // RNE, finite inputs
  return (u16)(r >> 16);
}

__device__ __forceinline__ void async_copy16(const u16* g, u16* l) {
  __builtin_amdgcn_global_load_lds((const __attribute__((address_space(1))) unsigned*)g,
                                   (__attribute__((address_space(3))) unsigned*)l,
                                   16, 0, 0);
}

// ---- K0: P = 2*Wr@emb^T [1024][16], c_e = 2*br.emb_e - |emb_e|^2 ----
__global__ void router_prep(const float* __restrict__ Wr, const float* __restrict__ br,
                            const float* __restrict__ emb, float* __restrict__ P,
                            float* __restrict__ c) {
  int idx = blockIdx.x * 256 + threadIdx.x;
  int row = idx >> 4, e = idx & 15;
  float s = 0.f;
  for (int j = 0; j < DEMB; ++j) s += Wr[row * DEMB + j] * emb[e * DEMB + j];
  P[row * NE + e] = 2.f * s;
  if (idx < NE) {
    float cc = 0.f, n2 = 0.f;
    for (int j = 0; j < DEMB; ++j) {
      float ev = emb[idx * DEMB + j];
      cc += br[j] * ev;
      n2 += ev * ev;
    }
    c[idx] = 2.f * cc - n2;
  }
}

// ---- K1: scores, top-2, gates; per-block LDS histogram -> bhist; xbf emit ----
__global__ void __launch_bounds__(256) router_score(
    const float* __restrict__ x, const float* __restrict__ P,
    const float* __restrict__ c, int* __restrict__ e01,
    float* __restrict__ g01, int* __restrict__ bhist,
    u16* __restrict__ xbf) {
  __shared__ float xs[16384];
  __shared__ int lh[16];
  int wave = threadIdx.x >> 6, lane = threadIdx.x & 63;
  int e2 = lane & 7, kgl = lane >> 3;
  int tbase = blockIdx.x * 16 + wave * 4;
  float* xw = xs + wave * 4096;

  if (threadIdx.x < 16) lh[threadIdx.x] = 0;

  // stage 4 token rows into LDS; emit bf16 copy to xbf on the way (free conversion)
  u16* xbrow = xbf + (size_t)tbase * DIN;
  #pragma unroll
  for (int t = 0; t < 4; ++t) {
    const float* src = x + (size_t)(tbase + t) * DIN;
    #pragma unroll
    for (int q = 0; q < 4; ++q) {
      int g = q * 256 + lane * 4;
      float4 v = *(const float4*)(src + g);
      *(float4*)(xw + t * 1024 + g) = v;
      ushort4 o;
      o.x = f2bf(v.x); o.y = f2bf(v.y); o.z = f2bf(v.z); o.w = f2bf(v.w);
      *(ushort4*)(xbrow + t * DIN + g) = o;
    }
  }
  __syncthreads();

  int te0 = 2 * e2, te1 = te0 + 1;
  float ce0 = c[te0], ce1 = c[te1];
  const float* Pb = P + te0;

  float acc0[4] = {0.f, 0.f, 0.f, 0.f};
  float acc1[4] = {0.f, 0.f, 0.f, 0.f};
  int cbase = kgl * 128;
  #pragma unroll 4
  for (int i = 0; i < 32; ++i) {
    int w = (kgl * 4 + i * 4) & 127;
    int idx = cbase + w;
    float2 pv0 = *(const float2*)(Pb + (size_t)(idx + 0) * NE);
    float2 pv1 = *(const float2*)(Pb + (size_t)(idx + 1) * NE);
    float2 pv2 = *(const float2*)(Pb + (size_t)(idx + 2) * NE);
    float2 pv3 = *(const float2*)(Pb + (size_t)(idx + 3) * NE);
    #pragma unroll
    for (int t = 0; t < 4; ++t) {
      float4 xv = *(const float4*)(xw + t * 1024 + idx);
      acc0[t] = fmaf(xv.x, pv0.x, acc0[t]); acc1[t] = fmaf(xv.x, pv0.y, acc1[t]);
      acc0[t] = fmaf(xv.y, pv1.x, acc0[t]); acc1[t] = fmaf(xv.y, pv1.y, acc1[t]);
      acc0[t] = fmaf(xv.z, pv2.x, acc0[t]); acc1[t] = fmaf(xv.z, pv2.y, acc1[t]);
      acc0[t] = fmaf(xv.w, pv3.x, acc0[t]); acc1[t] = fmaf(xv.w, pv3.y, acc1[t]);
    }
  }

  for (int t = 0; t < 4; ++t) {
    float s0 = acc0[t], s1 = acc1[t];
    #pragma unroll
    for (int off = 8; off <= 32; off <<= 1) {
      s0 += __shfl_xor(s0, off);
      s1 += __shfl_xor(s1, off);
    }
    s0 += ce0; s1 += ce1;
    float hi; int hidx;
    if (s0 >= s1) { hi = s0; hidx = te0; } else { hi = s1; hidx = te1; }
    float m1 = hi; int i1 = hidx;
    #pragma unroll
    for (int off = 1; off < 8; off <<= 1) {
      float so = __shfl_xor(m1, off); int io = __shfl_xor(i1, off);
      if (so > m1 || (so == m1 && io < i1)) { m1 = so; i1 = io; }
    }
    float c2; int c2i;
    if (i1 == te0)      { c2 = s1; c2i = te1; }
    else if (i1 == te1) { c2 = s0; c2i = te0; }
    else                { c2 = hi; c2i = hidx; }
    float m2 = c2; int i2 = c2i;
    #pragma unroll
    for (int off = 1; off < 8; off <<= 1) {
      float so = __shfl_xor(m2, off); int io = __shfl_xor(i2, off);
      if (so > m2 || (so == m2 && io < i2)) { m2 = so; i2 = io; }
    }
    if (lane == 0) {
      int tok = tbase + t;
      float ev = expf(m2 - m1);
      float inv = 1.f / (1.f + ev);
      e01[tok * 2 + 0] = i1; e01[tok * 2 + 1] = i2;
      g01[tok * 2 + 0] = inv; g01[tok * 2 + 1] = ev * inv;
      atomicAdd(&lh[i1], 1);
      atomicAdd(&lh[i2], 1);
    }
  }
  __syncthreads();
  if (threadIdx.x < 16) bhist[blockIdx.x * 16 + threadIdx.x] = lh[threadIdx.x];
}

// ---- K2: scan bhist -> counts, poff, per-block bases; zero-fill gtok pads ----
__global__ void __launch_bounds__(1024) scan_offsets(
    const int* __restrict__ bhist, int* __restrict__ counts,
    int* __restrict__ poff, int* __restrict__ bbase, int* __restrict__ gtok) {
  int t = threadIdx.x;
  int e = t & 15, ch = t >> 4;
  int b0 = ch * 16;
  int s = 0;
  #pragma unroll
  for (int i = 0; i < 16; ++i) s += bhist[(b0 + i) * 16 + e];
  __shared__ int part[64][16];
  __shared__ int chbase[64][16];
  __shared__ int cnt[16];
  __shared__ int pof[16];
  part[ch][e] = s;
  __syncthreads();
  if (t < 16) {
    int run = 0;
    for (int c2 = 0; c2 < 64; ++c2) { chbase[c2][t] = run; run += part[c2][t]; }
    cnt[t] = run;
  }
  __syncthreads();
  if (t == 0) {
    int off = 0;
    for (int e2 = 0; e2 < NE; ++e2) {
      pof[e2] = off;
      poff[e2] = off;
      counts[e2] = cnt[e2];
      off += (cnt[e2] + 127) & ~127;
    }
    poff[NE] = off;
  }
  __syncthreads();
  // zero-fill intra-expert pad slots of gtok (L1 indirection reads them; token 0 is safe,
  // pad output rows are culled at the final layer by the count mask)
  int padc = ((cnt[e] + 127) & ~127) - cnt[e];
  int pbase = pof[e] + cnt[e];
  if (ch < padc) gtok[pbase + ch] = 0;
  if (ch + 64 < padc) gtok[pbase + ch + 64] = 0;

  int run = pof[e] + chbase[ch][e];
  #pragma unroll
  for (int i = 0; i < 16; ++i) {
    bbase[(b0 + i) * 16 + e] = run;
    run += bhist[(b0 + i) * 16 + e];
  }
}

// ---- K3: CSR entry lists ----
__global__ void build_lists(const int* __restrict__ e01, const float* __restrict__ g01,
                            const int* __restrict__ bbase, int* __restrict__ gtok,
                            float* __restrict__ ggate) {
  __shared__ int pos[16];
  int tid = threadIdx.x;
  if (tid < 16) pos[tid] = bbase[blockIdx.x * 16 + tid];
  __syncthreads();
  if (tid < 16) {
    int t = blockIdx.x * 16 + tid;
    #pragma unroll
    for (int k = 0; k < 2; ++k) {
      int e = e01[t * 2 + k];
      int p = atomicAdd(&pos[e], 1);
      gtok[p] = t;
      ggate[p] = g01[t * 2 + k];
    }
  }
}

// ---- K5: weight convert+transpose: [E][K][N] f32 -> [E][N][K] bf16 ----
template<int K, int N>
__global__ void conv_w(const float* __restrict__ W, u16* __restrict__ WT) {
  __shared__ float tile[64][65];
  int e = blockIdx.z;
  int n0 = blockIdx.x * 64, k0 = blockIdx.y * 64;
  int tx = threadIdx.x & 63, ty = threadIdx.x >> 6;
  const float* Wb = W + (size_t)e * K * N;
  #pragma unroll
  for (int p = 0; p < 16; ++p) {
    int k = p * 4 + ty;
    tile[k][tx] = Wb[(size_t)(k0 + k) * N + n0 + tx];
  }
  __syncthreads();
  u16* WTb = WT + (size_t)e * N * K;
  #pragma unroll
  for (int p = 0; p < 16; ++p) {
    int n = p * 4 + ty;
    WTb[(size_t)(n0 + n) * K + k0 + tx] = f2bf(tile[tx][n]);
  }
}

// ---- GEMM: A x B_e (both K-contig bf16), r6-proven dbuf structure ----
// INDIR: A-rows resolved through gtok (token-major xbf) -> no gathered copy needed.
// T1 bijective XCD remap + source-permuted LDS swizzle (0 conflicts, verified).
// MODE 0: Cb = bf16(relu(acc+bias)); MODE 1: atomicAdd(out[token], gate*(acc+bias))
template<int MODE, bool INDIR>
__global__ void __launch_bounds__(256)
gemm_moe(const u16* __restrict__ A, const u16* __restrict__ Ball,
         const float* __restrict__ bias, u16* __restrict__ Cb, float* __restrict__ outF,
         const int* __restrict__ poff, const int* __restrict__ counts,
         const int* __restrict__ gtok, const float* __restrict__ ggate,
         int K, int N, int nblk) {
  __shared__ u16 Asm[2][4096];
  __shared__ u16 Bsm[2][4096];

  int bid = blockIdx.x;
  int q = nblk >> 3, r = nblk & 7;
  int xcd = bid & 7, sidx = bid >> 3;
  int wg = (xcd < r ? xcd * (q + 1) : r * (q + 1) + (xcd - r) * q) + sidx;
  int NB = N >> 7;
  int rb = wg / NB, nb = wg - rb * NB;   // nb fastest: same A-tile contiguous on one XCD

  int row_base = rb * 128;
  if (row_base >= poff[NE]) return;
  int e = 0;
  while (row_base >= poff[e + 1]) ++e;

  int tid = threadIdx.x;
  int wave = tid >> 6, lane = tid & 63;
  int wm = wave >> 1, wn = wave & 1;
  int fr = lane & 15, kq = lane >> 4;
  int n_base = nb * 128;

  const u16* Brow = Ball + (size_t)e * N * K + (size_t)n_base * K;

  // per-thread A/B row bases (2 rows each), chunk permutation (involution pair)
  int rr0 = tid >> 2, rr1 = rr0 + 64;
  int ch8 = ((tid & 3) ^ ((rr0 >> 1) & 3)) * 8;   // (rr>>1)&3 equal for rr0, rr0+64
  const u16 *a0, *a1;
  if constexpr (INDIR) {
    a0 = A + (size_t)gtok[row_base + rr0] * K;
    a1 = A + (size_t)gtok[row_base + rr1] * K;
  } else {
    a0 = A + (size_t)(row_base + rr0) * K;
    a1 = A + (size_t)(row_base + rr1) * K;
  }
  const u16* b0 = Brow + (size_t)rr0 * K;
  const u16* b1 = Brow + (size_t)rr1 * K;

  f32x4 acc[4][4];
  #pragma unroll
  for (int m = 0; m < 4; ++m)
    #pragma unroll
    for (int n = 0; n < 4; ++n)
      acc[m][n] = (f32x4){0.f, 0.f, 0.f, 0.f};

  int swz = (fr >> 1) & 3;

  auto stage_tile = [&](int buf, int kt) {
    async_copy16(a0 + kt + ch8, &Asm[buf][tid * 8]);
    async_copy16(a1 + kt + ch8, &Asm[buf][(256 + tid) * 8]);
    async_copy16(b0 + kt + ch8, &Bsm[buf][tid * 8]);
    async_copy16(b1 + kt + ch8, &Bsm[buf][(256 + tid) * 8]);
  };

  stage_tile(0, 0);
  __syncthreads();

  int nstep = K >> 5;
  int cur = 0;
  for (int s = 0; s < nstep; ++s) {
    if (s + 1 < nstep) stage_tile(cur ^ 1, (s + 1) << 5);
    short8 av[4], bv[4];
    #pragma unroll
    for (int m = 0; m < 4; ++m)
      av[m] = *(const short8*)(&Asm[cur][((wm * 64 + m * 16 + fr) * 4 + (kq ^ swz)) * 8]);
    #pragma unroll
    for (int n = 0; n < 4; ++n)
      bv[n] = *(const short8*)(&Bsm[cur][((wn * 64 + n * 16 + fr) * 4 + (kq ^ swz)) * 8]);
    #pragma unroll
    for (int m = 0; m < 4; ++m)
      #pragma unroll
      for (int n = 0; n < 4; ++n)
        acc[m][n] = __builtin_amdgcn_mfma_f32_16x16x32_bf16(av[m], bv[n], acc[m][n], 0, 0, 0);
    __syncthreads();
    cur ^= 1;
  }

  int crow = (lane >> 4) * 4;   // C/D: col=lane&15, row=(lane>>4)*4+reg
  int ccol = lane & 15;
  const float* be = bias + (size_t)e * N;
  if constexpr (MODE == 0) {
    #pragma unroll
    for (int m = 0; m < 4; ++m) {
      int gr0 = row_base + wm * 64 + m * 16 + crow;
      #pragma unroll
      for (int n = 0; n < 4; ++n) {
        int gc = n_base + wn * 64 + n * 16 + ccol;
        float bvs = be[gc];
        #pragma unroll
        for (int r2 = 0; r2 < 4; ++r2) {
          float v = acc[m][n][r2] + bvs;
          v = v > 0.f ? v : 0.f;
          Cb[(size_t)(gr0 + r2) * N + gc] = f2bf(v);
        }
      }
    }
  } else {
    int poe = poff[e], ce = counts[e];
    #pragma unroll
    for (int m = 0; m < 4; ++m) {
      int gr0 = row_base + wm * 64 + m * 16 + crow;
      int tk[4]; float gt[4]; bool vl[4];
      #pragma unroll
      for (int r2 = 0; r2 < 4; ++r2) {
        int gr = gr0 + r2;
        vl[r2] = (gr - poe) < ce;
        tk[r2] = vl[r2] ? gtok[gr] : 0;
        gt[r2] = vl[r2] ? ggate[gr] : 0.f;
      }
      #pragma unroll
      for (int n = 0; n < 4; ++n) {
        int gc = n_base + wn * 64 + n * 16 + ccol;
        float bvs = be[gc];
        #pragma unroll
        for (int r2 = 0; r2 < 4; ++r2) {
          if (vl[r2]) {
            float v = (acc[m][n][r2] + bvs) * gt[r2];
            atomicAdd(outF + (size_t)tk[r2] * N + gc, v);
          }
        }
      }
    }
  }
}

extern "C" void kernel_launch(void* const* d_in, const int* in_sizes, int n_in,
                              void* d_out, int out_size, void* d_ws, size_t ws_size,
                              hipStream_t stream) {
  const float* x   = (const float*)d_in[0];
  const float* Wr  = (const float*)d_in[1];
  const float* br  = (const float*)d_in[2];
  const float* emb = (const float*)d_in[3];
  const float* W1  = (const float*)d_in[4];
  const float* b1  = (const float*)d_in[5];
  const float* W2  = (const float*)d_in[6];
  const float* b2  = (const float*)d_in[7];
  const float* W3  = (const float*)d_in[8];
  const float* b3  = (const float*)d_in[9];
  float* out = (float*)d_out;
  char* ws = (char*)d_ws;

  float* P      = (float*)(ws + OFF_P);
  float* c      = (float*)(ws + OFF_C);
  int*   counts = (int*)(ws + OFF_CTRL);
  int*   poff   = (int*)(ws + OFF_CTRL + 128);
  int*   e01    = (int*)(ws + OFF_E01);
  float* g01    = (float*)(ws + OFF_G01);
  int*   gtok   = (int*)(ws + OFF_GTOK);
  float* ggate  = (float*)(ws + OFF_GGATE);
  int*   bhist  = (int*)(ws + OFF_BH);
  int*   bbase  = (int*)(ws + OFF_BB);
  u16*   W1T    = (u16*)(ws + OFF_W1T);
  u16*   W2T    = (u16*)(ws + OFF_W2T);
  u16*   W3T    = (u16*)(ws + OFF_W3T);
  u16*   xbf    = (u16*)(ws + OFF_XBF);
  u16*   h1     = (u16*)(ws + OFF_H1);
  u16*   h2     = (u16*)(ws + OFF_H2);

  hipMemsetAsync(d_out, 0, (size_t)N_TOK * DOUT * sizeof(float), stream);

  conv_w<DIN, H1N><<<dim3(H1N / 64, DIN / 64, NE), 256, 0, stream>>>(W1, W1T);
  conv_w<H1N, H2N><<<dim3(H2N / 64, H1N / 64, NE), 256, 0, stream>>>(W2, W2T);
  conv_w<H2N, DOUT><<<dim3(DOUT / 64, H2N / 64, NE), 256, 0, stream>>>(W3, W3T);

  router_prep<<<64, 256, 0, stream>>>(Wr, br, emb, P, c);
  router_score<<<RBLK, 256, 0, stream>>>(x, P, c, e01, g01, bhist, xbf);
  scan_offsets<<<1, 1024, 0, stream>>>(bhist, counts, poff, bbase, gtok);
  build_lists<<<RBLK, 64, 0, stream>>>(e01, g01, bbase, gtok, ggate);

  int nb1 = (H1N / 128) * MT;
  int nb2 = (H2N / 128) * MT;
  int nb3 = (DOUT / 128) * MT;
  gemm_moe<0, true><<<nb1, 256, 0, stream>>>(xbf, W1T, b1, h1, nullptr,
                                             poff, counts, gtok, nullptr, DIN, H1N, nb1);
  gemm_moe<0, false><<<nb2, 256, 0, stream>>>(h1, W2T, b2, h2, nullptr,
                                              poff, counts, nullptr, nullptr, H1N, H2N, nb2);
  gemm_moe<1, false><<<nb3, 256, 0, stream>>>(h2, W3T, b3, nullptr, out,
                                              poff, counts, gtok, ggate, H2N, DOUT, nb3);
}

// Round 8
// 291.772 us; speedup vs baseline: 1.5444x; 1.1759x over previous
//
#include <hip/hip_runtime.h>

typedef unsigned short u16;
typedef __attribute__((ext_vector_type(8))) short short8;
typedef __attribute__((ext_vector_type(4))) float f32x4;

#define N_TOK 16384
#define DIN   1024
#define NE    16
#define DEMB  128
#define H1N   1024
#define H2N   512
#define DOUT  512
#define CAP   34816   // 32768 entries + 16*128 padding
#define MT    (CAP/128)
#define RBLK  1024    // router blocks (16 tokens each)

// ---- workspace layout (bytes), alias-noted, ends 200,098,304 (< proven 201.9 MB) ----
#define OFF_P      0ul           // 65536
#define OFF_C      65536ul       // 256
#define OFF_CTRL   65792ul       // counts[16]@0, poff[17]@128 (256)
#define OFF_E01    66048ul       // 131072
#define OFF_G01    197120ul      // 131072
#define OFF_GTOK   328192ul      // CAP*4 = 139264
#define OFF_GGATE  467456ul      // 139264
#define OFF_TSLOT  606720ul      // N_TOK*2*4 = 131072
#define OFF_BH     737792ul      // 65536
#define OFF_BB     803328ul      // 65536
#define OFF_W1T    868864ul      // 33554432
#define OFF_W2T    34423296ul    // 16777216
#define OFF_W3T    51200512ul    // 8388608
#define OFF_XBF    59589120ul    // N_TOK*1024*2 = 33554432
#define OFF_H1     93143552ul    // CAP*1024*2 = 71303168
#define OFF_H2     164446720ul   // CAP*512*2  = 35651584
#define OFF_EO     OFF_H1        // eo f32 CAP*512*4 = 71303168 (h1 dead after L2)

__device__ __forceinline__ u16 f2bf(float f) {
  union { float f; unsigned u; } v; v.f = f;
  unsigned r = v.u + 0x7fff + ((v.u >> 16) & 1);   // RNE, finite inputs
  return (u16)(r >> 16);
}

__device__ __forceinline__ void async_copy16(const u16* g, u16* l) {
  __builtin_amdgcn_global_load_lds((const __attribute__((address_space(1))) unsigned*)g,
                                   (__attribute__((address_space(3))) unsigned*)l,
                                   16, 0, 0);
}

// ---- K0: P = 2*Wr@emb^T [1024][16], c_e = 2*br.emb_e - |emb_e|^2 ----
__global__ void router_prep(const float* __restrict__ Wr, const float* __restrict__ br,
                            const float* __restrict__ emb, float* __restrict__ P,
                            float* __restrict__ c) {
  int idx = blockIdx.x * 256 + threadIdx.x;
  int row = idx >> 4, e = idx & 15;
  float s = 0.f;
  for (int j = 0; j < DEMB; ++j) s += Wr[row * DEMB + j] * emb[e * DEMB + j];
  P[row * NE + e] = 2.f * s;
  if (idx < NE) {
    float cc = 0.f, n2 = 0.f;
    for (int j = 0; j < DEMB; ++j) {
      float ev = emb[idx * DEMB + j];
      cc += br[j] * ev;
      n2 += ev * ev;
    }
    c[idx] = 2.f * cc - n2;
  }
}

// ---- K1: scores, top-2, gates; per-block LDS histogram -> bhist; xbf emit ----
__global__ void __launch_bounds__(256) router_score(
    const float* __restrict__ x, const float* __restrict__ P,
    const float* __restrict__ c, int* __restrict__ e01,
    float* __restrict__ g01, int* __restrict__ bhist,
    u16* __restrict__ xbf) {
  __shared__ float xs[16384];
  __shared__ int lh[16];
  int wave = threadIdx.x >> 6, lane = threadIdx.x & 63;
  int e2 = lane & 7, kgl = lane >> 3;
  int tbase = blockIdx.x * 16 + wave * 4;
  float* xw = xs + wave * 4096;

  if (threadIdx.x < 16) lh[threadIdx.x] = 0;

  u16* xbrow = xbf + (size_t)tbase * DIN;
  #pragma unroll
  for (int t = 0; t < 4; ++t) {
    const float* src = x + (size_t)(tbase + t) * DIN;
    #pragma unroll
    for (int q = 0; q < 4; ++q) {
      int g = q * 256 + lane * 4;
      float4 v = *(const float4*)(src + g);
      *(float4*)(xw + t * 1024 + g) = v;
      ushort4 o;
      o.x = f2bf(v.x); o.y = f2bf(v.y); o.z = f2bf(v.z); o.w = f2bf(v.w);
      *(ushort4*)(xbrow + t * DIN + g) = o;
    }
  }
  __syncthreads();

  int te0 = 2 * e2, te1 = te0 + 1;
  float ce0 = c[te0], ce1 = c[te1];
  const float* Pb = P + te0;

  float acc0[4] = {0.f, 0.f, 0.f, 0.f};
  float acc1[4] = {0.f, 0.f, 0.f, 0.f};
  int cbase = kgl * 128;
  #pragma unroll 4
  for (int i = 0; i < 32; ++i) {
    int w = (kgl * 4 + i * 4) & 127;
    int idx = cbase + w;
    float2 pv0 = *(const float2*)(Pb + (size_t)(idx + 0) * NE);
    float2 pv1 = *(const float2*)(Pb + (size_t)(idx + 1) * NE);
    float2 pv2 = *(const float2*)(Pb + (size_t)(idx + 2) * NE);
    float2 pv3 = *(const float2*)(Pb + (size_t)(idx + 3) * NE);
    #pragma unroll
    for (int t = 0; t < 4; ++t) {
      float4 xv = *(const float4*)(xw + t * 1024 + idx);
      acc0[t] = fmaf(xv.x, pv0.x, acc0[t]); acc1[t] = fmaf(xv.x, pv0.y, acc1[t]);
      acc0[t] = fmaf(xv.y, pv1.x, acc0[t]); acc1[t] = fmaf(xv.y, pv1.y, acc1[t]);
      acc0[t] = fmaf(xv.z, pv2.x, acc0[t]); acc1[t] = fmaf(xv.z, pv2.y, acc1[t]);
      acc0[t] = fmaf(xv.w, pv3.x, acc0[t]); acc1[t] = fmaf(xv.w, pv3.y, acc1[t]);
    }
  }

  for (int t = 0; t < 4; ++t) {
    float s0 = acc0[t], s1 = acc1[t];
    #pragma unroll
    for (int off = 8; off <= 32; off <<= 1) {
      s0 += __shfl_xor(s0, off);
      s1 += __shfl_xor(s1, off);
    }
    s0 += ce0; s1 += ce1;
    float hi; int hidx;
    if (s0 >= s1) { hi = s0; hidx = te0; } else { hi = s1; hidx = te1; }
    float m1 = hi; int i1 = hidx;
    #pragma unroll
    for (int off = 1; off < 8; off <<= 1) {
      float so = __shfl_xor(m1, off); int io = __shfl_xor(i1, off);
      if (so > m1 || (so == m1 && io < i1)) { m1 = so; i1 = io; }
    }
    float c2; int c2i;
    if (i1 == te0)      { c2 = s1; c2i = te1; }
    else if (i1 == te1) { c2 = s0; c2i = te0; }
    else                { c2 = hi; c2i = hidx; }
    float m2 = c2; int i2 = c2i;
    #pragma unroll
    for (int off = 1; off < 8; off <<= 1) {
      float so = __shfl_xor(m2, off); int io = __shfl_xor(i2, off);
      if (so > m2 || (so == m2 && io < i2)) { m2 = so; i2 = io; }
    }
    if (lane == 0) {
      int tok = tbase + t;
      float ev = expf(m2 - m1);
      float inv = 1.f / (1.f + ev);
      e01[tok * 2 + 0] = i1; e01[tok * 2 + 1] = i2;
      g01[tok * 2 + 0] = inv; g01[tok * 2 + 1] = ev * inv;
      atomicAdd(&lh[i1], 1);
      atomicAdd(&lh[i2], 1);
    }
  }
  __syncthreads();
  if (threadIdx.x < 16) bhist[blockIdx.x * 16 + threadIdx.x] = lh[threadIdx.x];
}

// ---- K2: scan bhist -> counts, poff, per-block bases; zero-fill gtok pads ----
__global__ void __launch_bounds__(1024) scan_offsets(
    const int* __restrict__ bhist, int* __restrict__ counts,
    int* __restrict__ poff, int* __restrict__ bbase, int* __restrict__ gtok) {
  int t = threadIdx.x;
  int e = t & 15, ch = t >> 4;
  int b0 = ch * 16;
  int s = 0;
  #pragma unroll
  for (int i = 0; i < 16; ++i) s += bhist[(b0 + i) * 16 + e];
  __shared__ int part[64][16];
  __shared__ int chbase[64][16];
  __shared__ int cnt[16];
  __shared__ int pof[16];
  part[ch][e] = s;
  __syncthreads();
  if (t < 16) {
    int run = 0;
    for (int c2 = 0; c2 < 64; ++c2) { chbase[c2][t] = run; run += part[c2][t]; }
    cnt[t] = run;
  }
  __syncthreads();
  if (t == 0) {
    int off = 0;
    for (int e2 = 0; e2 < NE; ++e2) {
      pof[e2] = off;
      poff[e2] = off;
      counts[e2] = cnt[e2];
      off += (cnt[e2] + 127) & ~127;
    }
    poff[NE] = off;
  }
  __syncthreads();
  // zero-fill intra-expert pad slots of gtok (L1 indirection reads them; token 0 safe)
  int padc = ((cnt[e] + 127) & ~127) - cnt[e];
  int pbase = pof[e] + cnt[e];
  if (ch < padc) gtok[pbase + ch] = 0;
  if (ch + 64 < padc) gtok[pbase + ch + 64] = 0;

  int run = pof[e] + chbase[ch][e];
  #pragma unroll
  for (int i = 0; i < 16; ++i) {
    bbase[(b0 + i) * 16 + e] = run;
    run += bhist[(b0 + i) * 16 + e];
  }
}

// ---- K3: CSR entry lists + inverse map tslot[t*2+k] = slot ----
__global__ void build_lists(const int* __restrict__ e01, const float* __restrict__ g01,
                            const int* __restrict__ bbase, int* __restrict__ gtok,
                            float* __restrict__ ggate, int* __restrict__ tslot) {
  __shared__ int pos[16];
  int tid = threadIdx.x;
  if (tid < 16) pos[tid] = bbase[blockIdx.x * 16 + tid];
  __syncthreads();
  if (tid < 16) {
    int t = blockIdx.x * 16 + tid;
    #pragma unroll
    for (int k = 0; k < 2; ++k) {
      int e = e01[t * 2 + k];
      int p = atomicAdd(&pos[e], 1);
      gtok[p] = t;
      ggate[p] = g01[t * 2 + k];
      tslot[t * 2 + k] = p;
    }
  }
}

// ---- K5: weight convert+transpose: [E][K][N] f32 -> [E][N][K] bf16 ----
template<int K, int N>
__global__ void conv_w(const float* __restrict__ W, u16* __restrict__ WT) {
  __shared__ float tile[64][65];
  int e = blockIdx.z;
  int n0 = blockIdx.x * 64, k0 = blockIdx.y * 64;
  int tx = threadIdx.x & 63, ty = threadIdx.x >> 6;
  const float* Wb = W + (size_t)e * K * N;
  #pragma unroll
  for (int p = 0; p < 16; ++p) {
    int k = p * 4 + ty;
    tile[k][tx] = Wb[(size_t)(k0 + k) * N + n0 + tx];
  }
  __syncthreads();
  u16* WTb = WT + (size_t)e * N * K;
  #pragma unroll
  for (int p = 0; p < 16; ++p) {
    int n = p * 4 + ty;
    WTb[(size_t)(n0 + n) * K + k0 + tx] = f2bf(tile[tx][n]);
  }
}

// ---- GEMM: A x B_e (both K-contig bf16), r6-proven dbuf structure ----
// INDIR: A-rows resolved through gtok (token-major xbf).
// MODE 0: Cb = bf16(relu(acc+bias)); MODE 2: eoF[row] = f32(acc+bias) plain store
template<int MODE, bool INDIR>
__global__ void __launch_bounds__(256)
gemm_moe(const u16* __restrict__ A, const u16* __restrict__ Ball,
         const float* __restrict__ bias, u16* __restrict__ Cb, float* __restrict__ outF,
         const int* __restrict__ poff, const int* __restrict__ counts,
         const int* __restrict__ gtok, const float* __restrict__ ggate,
         int K, int N, int nblk) {
  __shared__ u16 Asm[2][4096];
  __shared__ u16 Bsm[2][4096];

  int bid = blockIdx.x;
  int q = nblk >> 3, r = nblk & 7;
  int xcd = bid & 7, sidx = bid >> 3;
  int wg = (xcd < r ? xcd * (q + 1) : r * (q + 1) + (xcd - r) * q) + sidx;
  int NB = N >> 7;
  int rb = wg / NB, nb = wg - rb * NB;

  int row_base = rb * 128;
  if (row_base >= poff[NE]) return;
  int e = 0;
  while (row_base >= poff[e + 1]) ++e;

  int tid = threadIdx.x;
  int wave = tid >> 6, lane = tid & 63;
  int wm = wave >> 1, wn = wave & 1;
  int fr = lane & 15, kq = lane >> 4;
  int n_base = nb * 128;

  const u16* Brow = Ball + (size_t)e * N * K + (size_t)n_base * K;

  int rr0 = tid >> 2, rr1 = rr0 + 64;
  int ch8 = ((tid & 3) ^ ((rr0 >> 1) & 3)) * 8;
  const u16 *a0, *a1;
  if constexpr (INDIR) {
    a0 = A + (size_t)gtok[row_base + rr0] * K;
    a1 = A + (size_t)gtok[row_base + rr1] * K;
  } else {
    a0 = A + (size_t)(row_base + rr0) * K;
    a1 = A + (size_t)(row_base + rr1) * K;
  }
  const u16* b0 = Brow + (size_t)rr0 * K;
  const u16* b1 = Brow + (size_t)rr1 * K;

  f32x4 acc[4][4];
  #pragma unroll
  for (int m = 0; m < 4; ++m)
    #pragma unroll
    for (int n = 0; n < 4; ++n)
      acc[m][n] = (f32x4){0.f, 0.f, 0.f, 0.f};

  int swz = (fr >> 1) & 3;

  auto stage_tile = [&](int buf, int kt) {
    async_copy16(a0 + kt + ch8, &Asm[buf][tid * 8]);
    async_copy16(a1 + kt + ch8, &Asm[buf][(256 + tid) * 8]);
    async_copy16(b0 + kt + ch8, &Bsm[buf][tid * 8]);
    async_copy16(b1 + kt + ch8, &Bsm[buf][(256 + tid) * 8]);
  };

  stage_tile(0, 0);
  __syncthreads();

  int nstep = K >> 5;
  int cur = 0;
  for (int s = 0; s < nstep; ++s) {
    if (s + 1 < nstep) stage_tile(cur ^ 1, (s + 1) << 5);
    short8 av[4], bv[4];
    #pragma unroll
    for (int m = 0; m < 4; ++m)
      av[m] = *(const short8*)(&Asm[cur][((wm * 64 + m * 16 + fr) * 4 + (kq ^ swz)) * 8]);
    #pragma unroll
    for (int n = 0; n < 4; ++n)
      bv[n] = *(const short8*)(&Bsm[cur][((wn * 64 + n * 16 + fr) * 4 + (kq ^ swz)) * 8]);
    #pragma unroll
    for (int m = 0; m < 4; ++m)
      #pragma unroll
      for (int n = 0; n < 4; ++n)
        acc[m][n] = __builtin_amdgcn_mfma_f32_16x16x32_bf16(av[m], bv[n], acc[m][n], 0, 0, 0);
    __syncthreads();
    cur ^= 1;
  }

  int crow = (lane >> 4) * 4;   // C/D: col=lane&15, row=(lane>>4)*4+reg
  int ccol = lane & 15;
  const float* be = bias + (size_t)e * N;
  if constexpr (MODE == 0) {
    #pragma unroll
    for (int m = 0; m < 4; ++m) {
      int gr0 = row_base + wm * 64 + m * 16 + crow;
      #pragma unroll
      for (int n = 0; n < 4; ++n) {
        int gc = n_base + wn * 64 + n * 16 + ccol;
        float bvs = be[gc];
        #pragma unroll
        for (int r2 = 0; r2 < 4; ++r2) {
          float v = acc[m][n][r2] + bvs;
          v = v > 0.f ? v : 0.f;
          Cb[(size_t)(gr0 + r2) * N + gc] = f2bf(v);
        }
      }
    }
  } else {
    // MODE 2: plain f32 store (pad rows written but never read via tslot)
    #pragma unroll
    for (int m = 0; m < 4; ++m) {
      int gr0 = row_base + wm * 64 + m * 16 + crow;
      #pragma unroll
      for (int n = 0; n < 4; ++n) {
        int gc = n_base + wn * 64 + n * 16 + ccol;
        float bvs = be[gc];
        #pragma unroll
        for (int r2 = 0; r2 < 4; ++r2)
          outF[(size_t)(gr0 + r2) * N + gc] = acc[m][n][r2] + bvs;
      }
    }
  }
}

// ---- K7: combine — one wave per token: out[t] = g0*eo[s0] + g1*eo[s1] ----
__global__ void __launch_bounds__(256) combine_out(
    const float* __restrict__ eo, const int* __restrict__ tslot,
    const float* __restrict__ g01, float* __restrict__ out) {
  int wave = threadIdx.x >> 6, lane = threadIdx.x & 63;
  int tok = blockIdx.x * 4 + wave;
  int s0 = tslot[tok * 2 + 0], s1 = tslot[tok * 2 + 1];
  float g0 = g01[tok * 2 + 0], g1 = g01[tok * 2 + 1];
  const float* r0 = eo + (size_t)s0 * DOUT + lane * 8;
  const float* r1 = eo + (size_t)s1 * DOUT + lane * 8;
  float* o = out + (size_t)tok * DOUT + lane * 8;
  #pragma unroll
  for (int j = 0; j < 2; ++j) {
    float4 v0 = ((const float4*)r0)[j];
    float4 v1 = ((const float4*)r1)[j];
    float4 ov;
    ov.x = g0 * v0.x + g1 * v1.x;
    ov.y = g0 * v0.y + g1 * v1.y;
    ov.z = g0 * v0.z + g1 * v1.z;
    ov.w = g0 * v0.w + g1 * v1.w;
    ((float4*)o)[j] = ov;
  }
}

extern "C" void kernel_launch(void* const* d_in, const int* in_sizes, int n_in,
                              void* d_out, int out_size, void* d_ws, size_t ws_size,
                              hipStream_t stream) {
  const float* x   = (const float*)d_in[0];
  const float* Wr  = (const float*)d_in[1];
  const float* br  = (const float*)d_in[2];
  const float* emb = (const float*)d_in[3];
  const float* W1  = (const float*)d_in[4];
  const float* b1  = (const float*)d_in[5];
  const float* W2  = (const float*)d_in[6];
  const float* b2  = (const float*)d_in[7];
  const float* W3  = (const float*)d_in[8];
  const float* b3  = (const float*)d_in[9];
  float* out = (float*)d_out;
  char* ws = (char*)d_ws;

  float* P      = (float*)(ws + OFF_P);
  float* c      = (float*)(ws + OFF_C);
  int*   counts = (int*)(ws + OFF_CTRL);
  int*   poff   = (int*)(ws + OFF_CTRL + 128);
  int*   e01    = (int*)(ws + OFF_E01);
  float* g01    = (float*)(ws + OFF_G01);
  int*   gtok   = (int*)(ws + OFF_GTOK);
  float* ggate  = (float*)(ws + OFF_GGATE);
  int*   tslot  = (int*)(ws + OFF_TSLOT);
  int*   bhist  = (int*)(ws + OFF_BH);
  int*   bbase  = (int*)(ws + OFF_BB);
  u16*   W1T    = (u16*)(ws + OFF_W1T);
  u16*   W2T    = (u16*)(ws + OFF_W2T);
  u16*   W3T    = (u16*)(ws + OFF_W3T);
  u16*   xbf    = (u16*)(ws + OFF_XBF);
  u16*   h1     = (u16*)(ws + OFF_H1);
  u16*   h2     = (u16*)(ws + OFF_H2);
  float* eo     = (float*)(ws + OFF_EO);

  conv_w<DIN, H1N><<<dim3(H1N / 64, DIN / 64, NE), 256, 0, stream>>>(W1, W1T);
  conv_w<H1N, H2N><<<dim3(H2N / 64, H1N / 64, NE), 256, 0, stream>>>(W2, W2T);
  conv_w<H2N, DOUT><<<dim3(DOUT / 64, H2N / 64, NE), 256, 0, stream>>>(W3, W3T);

  router_prep<<<64, 256, 0, stream>>>(Wr, br, emb, P, c);
  router_score<<<RBLK, 256, 0, stream>>>(x, P, c, e01, g01, bhist, xbf);
  scan_offsets<<<1, 1024, 0, stream>>>(bhist, counts, poff, bbase, gtok);
  build_lists<<<RBLK, 64, 0, stream>>>(e01, g01, bbase, gtok, ggate, tslot);

  int nb1 = (H1N / 128) * MT;
  int nb2 = (H2N / 128) * MT;
  int nb3 = (DOUT / 128) * MT;
  gemm_moe<0, true><<<nb1, 256, 0, stream>>>(xbf, W1T, b1, h1, nullptr,
                                             poff, counts, gtok, nullptr, DIN, H1N, nb1);
  gemm_moe<0, false><<<nb2, 256, 0, stream>>>(h1, W2T, b2, h2, nullptr,
                                              poff, counts, nullptr, nullptr, H1N, H2N, nb2);
  gemm_moe<2, false><<<nb3, 256, 0, stream>>>(h2, W3T, b3, nullptr, eo,
                                              poff, counts, nullptr, nullptr, H2N, DOUT, nb3);
  combine_out<<<N_TOK / 4, 256, 0, stream>>>(eo, tslot, g01, out);
}

// Round 9
// 286.476 us; speedup vs baseline: 1.5730x; 1.0185x over previous
//
#include <hip/hip_runtime.h>

typedef unsigned short u16;
typedef __attribute__((ext_vector_type(8))) short short8;
typedef __attribute__((ext_vector_type(4))) float f32x4;

#define N_TOK 16384
#define DIN   1024
#define NE    16
#define DEMB  128
#define H1N   1024
#define H2N   512
#define DOUT  512
#define CAP   34816   // 32768 entries + 16*128 padding
#define MT    (CAP/128)
#define RBLK  1024    // router blocks (16 tokens each)

// ---- workspace layout (bytes), ends 200,098,304 (< proven 201.9 MB) ----
#define OFF_P      0ul           // 65536
#define OFF_C      65536ul       // 256
#define OFF_CTRL   65792ul       // counts[16]@0, poff[17]@128 (256)
#define OFF_E01    66048ul       // 131072
#define OFF_G01    197120ul      // 131072
#define OFF_GTOK   328192ul      // CAP*4 = 139264
#define OFF_GGATE  467456ul      // 139264
#define OFF_TSLOT  606720ul      // N_TOK*2*4 = 131072
#define OFF_BH     737792ul      // 65536
#define OFF_BB     803328ul      // 65536
#define OFF_W1T    868864ul      // 33554432
#define OFF_W2T    34423296ul    // 16777216
#define OFF_W3T    51200512ul    // 8388608
#define OFF_XBF    59589120ul    // N_TOK*1024*2 = 33554432
#define OFF_H1     93143552ul    // CAP*1024*2 = 71303168
#define OFF_H2     164446720ul   // CAP*512*2  = 35651584
#define OFF_EO     OFF_H1        // eo f32 CAP*512*4 = 71303168 (h1 dead after L2)

__device__ __forceinline__ u16 f2bf(float f) {
  union { float f; unsigned u; } v; v.f = f;
  unsigned r = v.u + 0x7fff + ((v.u >> 16) & 1);   // RNE, finite inputs
  return (u16)(r >> 16);
}

__device__ __forceinline__ void async_copy16(const u16* g, u16* l) {
  __builtin_amdgcn_global_load_lds((const __attribute__((address_space(1))) unsigned*)g,
                                   (__attribute__((address_space(3))) unsigned*)l,
                                   16, 0, 0);
}

// ---- K0: P = 2*Wr@emb^T [1024][16], c_e = 2*br.emb_e - |emb_e|^2 ----
__global__ void router_prep(const float* __restrict__ Wr, const float* __restrict__ br,
                            const float* __restrict__ emb, float* __restrict__ P,
                            float* __restrict__ c) {
  int idx = blockIdx.x * 256 + threadIdx.x;
  int row = idx >> 4, e = idx & 15;
  float s = 0.f;
  for (int j = 0; j < DEMB; ++j) s += Wr[row * DEMB + j] * emb[e * DEMB + j];
  P[row * NE + e] = 2.f * s;
  if (idx < NE) {
    float cc = 0.f, n2 = 0.f;
    for (int j = 0; j < DEMB; ++j) {
      float ev = emb[idx * DEMB + j];
      cc += br[j] * ev;
      n2 += ev * ev;
    }
    c[idx] = 2.f * cc - n2;
  }
}

// ---- K1: scores, top-2, gates; per-block LDS histogram -> bhist; xbf emit ----
__global__ void __launch_bounds__(256) router_score(
    const float* __restrict__ x, const float* __restrict__ P,
    const float* __restrict__ c, int* __restrict__ e01,
    float* __restrict__ g01, int* __restrict__ bhist,
    u16* __restrict__ xbf) {
  __shared__ float xs[16384];
  __shared__ int lh[16];
  int wave = threadIdx.x >> 6, lane = threadIdx.x & 63;
  int e2 = lane & 7, kgl = lane >> 3;
  int tbase = blockIdx.x * 16 + wave * 4;
  float* xw = xs + wave * 4096;

  if (threadIdx.x < 16) lh[threadIdx.x] = 0;

  u16* xbrow = xbf + (size_t)tbase * DIN;
  #pragma unroll
  for (int t = 0; t < 4; ++t) {
    const float* src = x + (size_t)(tbase + t) * DIN;
    #pragma unroll
    for (int q = 0; q < 4; ++q) {
      int g = q * 256 + lane * 4;
      float4 v = *(const float4*)(src + g);
      *(float4*)(xw + t * 1024 + g) = v;
      ushort4 o;
      o.x = f2bf(v.x); o.y = f2bf(v.y); o.z = f2bf(v.z); o.w = f2bf(v.w);
      *(ushort4*)(xbrow + t * DIN + g) = o;
    }
  }
  __syncthreads();

  int te0 = 2 * e2, te1 = te0 + 1;
  float ce0 = c[te0], ce1 = c[te1];
  const float* Pb = P + te0;

  float acc0[4] = {0.f, 0.f, 0.f, 0.f};
  float acc1[4] = {0.f, 0.f, 0.f, 0.f};
  int cbase = kgl * 128;
  #pragma unroll 4
  for (int i = 0; i < 32; ++i) {
    int w = (kgl * 4 + i * 4) & 127;
    int idx = cbase + w;
    float2 pv0 = *(const float2*)(Pb + (size_t)(idx + 0) * NE);
    float2 pv1 = *(const float2*)(Pb + (size_t)(idx + 1) * NE);
    float2 pv2 = *(const float2*)(Pb + (size_t)(idx + 2) * NE);
    float2 pv3 = *(const float2*)(Pb + (size_t)(idx + 3) * NE);
    #pragma unroll
    for (int t = 0; t < 4; ++t) {
      float4 xv = *(const float4*)(xw + t * 1024 + idx);
      acc0[t] = fmaf(xv.x, pv0.x, acc0[t]); acc1[t] = fmaf(xv.x, pv0.y, acc1[t]);
      acc0[t] = fmaf(xv.y, pv1.x, acc0[t]); acc1[t] = fmaf(xv.y, pv1.y, acc1[t]);
      acc0[t] = fmaf(xv.z, pv2.x, acc0[t]); acc1[t] = fmaf(xv.z, pv2.y, acc1[t]);
      acc0[t] = fmaf(xv.w, pv3.x, acc0[t]); acc1[t] = fmaf(xv.w, pv3.y, acc1[t]);
    }
  }

  for (int t = 0; t < 4; ++t) {
    float s0 = acc0[t], s1 = acc1[t];
    #pragma unroll
    for (int off = 8; off <= 32; off <<= 1) {
      s0 += __shfl_xor(s0, off);
      s1 += __shfl_xor(s1, off);
    }
    s0 += ce0; s1 += ce1;
    float hi; int hidx;
    if (s0 >= s1) { hi = s0; hidx = te0; } else { hi = s1; hidx = te1; }
    float m1 = hi; int i1 = hidx;
    #pragma unroll
    for (int off = 1; off < 8; off <<= 1) {
      float so = __shfl_xor(m1, off); int io = __shfl_xor(i1, off);
      if (so > m1 || (so == m1 && io < i1)) { m1 = so; i1 = io; }
    }
    float c2; int c2i;
    if (i1 == te0)      { c2 = s1; c2i = te1; }
    else if (i1 == te1) { c2 = s0; c2i = te0; }
    else                { c2 = hi; c2i = hidx; }
    float m2 = c2; int i2 = c2i;
    #pragma unroll
    for (int off = 1; off < 8; off <<= 1) {
      float so = __shfl_xor(m2, off); int io = __shfl_xor(i2, off);
      if (so > m2 || (so == m2 && io < i2)) { m2 = so; i2 = io; }
    }
    if (lane == 0) {
      int tok = tbase + t;
      float ev = expf(m2 - m1);
      float inv = 1.f / (1.f + ev);
      e01[tok * 2 + 0] = i1; e01[tok * 2 + 1] = i2;
      g01[tok * 2 + 0] = inv; g01[tok * 2 + 1] = ev * inv;
      atomicAdd(&lh[i1], 1);
      atomicAdd(&lh[i2], 1);
    }
  }
  __syncthreads();
  if (threadIdx.x < 16) bhist[blockIdx.x * 16 + threadIdx.x] = lh[threadIdx.x];
}

// ---- K2: scan bhist -> counts, poff, per-block bases; zero-fill gtok pads ----
__global__ void __launch_bounds__(1024) scan_offsets(
    const int* __restrict__ bhist, int* __restrict__ counts,
    int* __restrict__ poff, int* __restrict__ bbase, int* __restrict__ gtok) {
  int t = threadIdx.x;
  int e = t & 15, ch = t >> 4;
  int b0 = ch * 16;
  int s = 0;
  #pragma unroll
  for (int i = 0; i < 16; ++i) s += bhist[(b0 + i) * 16 + e];
  __shared__ int part[64][16];
  __shared__ int chbase[64][16];
  __shared__ int cnt[16];
  __shared__ int pof[16];
  part[ch][e] = s;
  __syncthreads();
  if (t < 16) {
    int run = 0;
    for (int c2 = 0; c2 < 64; ++c2) { chbase[c2][t] = run; run += part[c2][t]; }
    cnt[t] = run;
  }
  __syncthreads();
  if (t == 0) {
    int off = 0;
    for (int e2 = 0; e2 < NE; ++e2) {
      pof[e2] = off;
      poff[e2] = off;
      counts[e2] = cnt[e2];
      off += (cnt[e2] + 127) & ~127;
    }
    poff[NE] = off;
  }
  __syncthreads();
  // zero-fill intra-expert pad slots of gtok (L1 indirection reads them; token 0 safe)
  int padc = ((cnt[e] + 127) & ~127) - cnt[e];
  int pbase = pof[e] + cnt[e];
  if (ch < padc) gtok[pbase + ch] = 0;
  if (ch + 64 < padc) gtok[pbase + ch + 64] = 0;

  int run = pof[e] + chbase[ch][e];
  #pragma unroll
  for (int i = 0; i < 16; ++i) {
    bbase[(b0 + i) * 16 + e] = run;
    run += bhist[(b0 + i) * 16 + e];
  }
}

// ---- K3: CSR entry lists + inverse map tslot[t*2+k] = slot ----
__global__ void build_lists(const int* __restrict__ e01, const float* __restrict__ g01,
                            const int* __restrict__ bbase, int* __restrict__ gtok,
                            float* __restrict__ ggate, int* __restrict__ tslot) {
  __shared__ int pos[16];
  int tid = threadIdx.x;
  if (tid < 16) pos[tid] = bbase[blockIdx.x * 16 + tid];
  __syncthreads();
  if (tid < 16) {
    int t = blockIdx.x * 16 + tid;
    #pragma unroll
    for (int k = 0; k < 2; ++k) {
      int e = e01[t * 2 + k];
      int p = atomicAdd(&pos[e], 1);
      gtok[p] = t;
      ggate[p] = g01[t * 2 + k];
      tslot[t * 2 + k] = p;
    }
  }
}

// ---- K5: weight convert+transpose: [E][K][N] f32 -> [E][N][K] bf16 ----
template<int K, int N>
__global__ void conv_w(const float* __restrict__ W, u16* __restrict__ WT) {
  __shared__ float tile[64][65];
  int e = blockIdx.z;
  int n0 = blockIdx.x * 64, k0 = blockIdx.y * 64;
  int tx = threadIdx.x & 63, ty = threadIdx.x >> 6;
  const float* Wb = W + (size_t)e * K * N;
  #pragma unroll
  for (int p = 0; p < 16; ++p) {
    int k = p * 4 + ty;
    tile[k][tx] = Wb[(size_t)(k0 + k) * N + n0 + tx];
  }
  __syncthreads();
  u16* WTb = WT + (size_t)e * N * K;
  #pragma unroll
  for (int p = 0; p < 16; ++p) {
    int n = p * 4 + ty;
    WTb[(size_t)(n0 + n) * K + k0 + tx] = f2bf(tile[tx][n]);
  }
}

// ---- GEMM: A x B_e (both K-contig bf16) ----
// T4 counted-vmcnt, 3-buffer rotation: tiles t,t+1 always in flight (4 loads each);
// per iter: vmcnt(4)+s_barrier (FIFO => tile t landed, all waves), stage t+2 into
// the buffer whose readers all passed this barrier, ds_read tile t, MFMA.
// Last iter: vmcnt(0) (nothing staged behind it). Loads never drain to 0 mid-loop.
// INDIR: A-rows resolved through gtok (token-major xbf).
// MODE 0: Cb = bf16(relu(acc+bias)); MODE 2: eoF[row] = f32(acc+bias) plain store
template<int MODE, bool INDIR>
__global__ void __launch_bounds__(256)
gemm_moe(const u16* __restrict__ A, const u16* __restrict__ Ball,
         const float* __restrict__ bias, u16* __restrict__ Cb, float* __restrict__ outF,
         const int* __restrict__ poff, const int* __restrict__ counts,
         const int* __restrict__ gtok, const float* __restrict__ ggate,
         int K, int N, int nblk) {
  __shared__ u16 Asm[3][4096];
  __shared__ u16 Bsm[3][4096];

  int bid = blockIdx.x;
  int q = nblk >> 3, r = nblk & 7;
  int xcd = bid & 7, sidx = bid >> 3;
  int wg = (xcd < r ? xcd * (q + 1) : r * (q + 1) + (xcd - r) * q) + sidx;
  int NB = N >> 7;
  int rb = wg / NB, nb = wg - rb * NB;

  int row_base = rb * 128;
  if (row_base >= poff[NE]) return;
  int e = 0;
  while (row_base >= poff[e + 1]) ++e;

  int tid = threadIdx.x;
  int wave = tid >> 6, lane = tid & 63;
  int wm = wave >> 1, wn = wave & 1;
  int fr = lane & 15, kq = lane >> 4;
  int n_base = nb * 128;

  const u16* Brow = Ball + (size_t)e * N * K + (size_t)n_base * K;

  int rr0 = tid >> 2, rr1 = rr0 + 64;
  int ch8 = ((tid & 3) ^ ((rr0 >> 1) & 3)) * 8;
  const u16 *a0, *a1;
  if constexpr (INDIR) {
    a0 = A + (size_t)gtok[row_base + rr0] * K;
    a1 = A + (size_t)gtok[row_base + rr1] * K;
  } else {
    a0 = A + (size_t)(row_base + rr0) * K;
    a1 = A + (size_t)(row_base + rr1) * K;
  }
  const u16* b0 = Brow + (size_t)rr0 * K;
  const u16* b1 = Brow + (size_t)rr1 * K;

  f32x4 acc[4][4];
  #pragma unroll
  for (int m = 0; m < 4; ++m)
    #pragma unroll
    for (int n = 0; n < 4; ++n)
      acc[m][n] = (f32x4){0.f, 0.f, 0.f, 0.f};

  int swz = (fr >> 1) & 3;

  auto stage_tile = [&](int buf, int kt) {
    async_copy16(a0 + kt + ch8, &Asm[buf][tid * 8]);
    async_copy16(a1 + kt + ch8, &Asm[buf][(256 + tid) * 8]);
    async_copy16(b0 + kt + ch8, &Bsm[buf][tid * 8]);
    async_copy16(b1 + kt + ch8, &Bsm[buf][(256 + tid) * 8]);
  };

  // prologue: tiles 0,1 in flight
  stage_tile(0, 0);
  stage_tile(1, 32);

  int nstep = K >> 5;
  int rd = 0, st = 2;
  for (int s = 0; s < nstep; ++s) {
    if (s == nstep - 1)
      asm volatile("s_waitcnt vmcnt(0)\n\ts_barrier" ::: "memory");
    else
      asm volatile("s_waitcnt vmcnt(4)\n\ts_barrier" ::: "memory");
    if (s + 2 < nstep) stage_tile(st, (s + 2) << 5);
    short8 av[4], bv[4];
    #pragma unroll
    for (int m = 0; m < 4; ++m)
      av[m] = *(const short8*)(&Asm[rd][((wm * 64 + m * 16 + fr) * 4 + (kq ^ swz)) * 8]);
    #pragma unroll
    for (int n = 0; n < 4; ++n)
      bv[n] = *(const short8*)(&Bsm[rd][((wn * 64 + n * 16 + fr) * 4 + (kq ^ swz)) * 8]);
    #pragma unroll
    for (int m = 0; m < 4; ++m)
      #pragma unroll
      for (int n = 0; n < 4; ++n)
        acc[m][n] = __builtin_amdgcn_mfma_f32_16x16x32_bf16(av[m], bv[n], acc[m][n], 0, 0, 0);
    rd = rd == 2 ? 0 : rd + 1;
    st = st == 2 ? 0 : st + 1;
  }

  int crow = (lane >> 4) * 4;   // C/D: col=lane&15, row=(lane>>4)*4+reg
  int ccol = lane & 15;
  const float* be = bias + (size_t)e * N;
  if constexpr (MODE == 0) {
    #pragma unroll
    for (int m = 0; m < 4; ++m) {
      int gr0 = row_base + wm * 64 + m * 16 + crow;
      #pragma unroll
      for (int n = 0; n < 4; ++n) {
        int gc = n_base + wn * 64 + n * 16 + ccol;
        float bvs = be[gc];
        #pragma unroll
        for (int r2 = 0; r2 < 4; ++r2) {
          float v = acc[m][n][r2] + bvs;
          v = v > 0.f ? v : 0.f;
          Cb[(size_t)(gr0 + r2) * N + gc] = f2bf(v);
        }
      }
    }
  } else {
    // MODE 2: plain f32 store (pad rows written but never read via tslot)
    #pragma unroll
    for (int m = 0; m < 4; ++m) {
      int gr0 = row_base + wm * 64 + m * 16 + crow;
      #pragma unroll
      for (int n = 0; n < 4; ++n) {
        int gc = n_base + wn * 64 + n * 16 + ccol;
        float bvs = be[gc];
        #pragma unroll
        for (int r2 = 0; r2 < 4; ++r2)
          outF[(size_t)(gr0 + r2) * N + gc] = acc[m][n][r2] + bvs;
      }
    }
  }
}

// ---- K7: combine — one wave per token: out[t] = g0*eo[s0] + g1*eo[s1] ----
__global__ void __launch_bounds__(256) combine_out(
    const float* __restrict__ eo, const int* __restrict__ tslot,
    const float* __restrict__ g01, float* __restrict__ out) {
  int wave = threadIdx.x >> 6, lane = threadIdx.x & 63;
  int tok = blockIdx.x * 4 + wave;
  int s0 = tslot[tok * 2 + 0], s1 = tslot[tok * 2 + 1];
  float g0 = g01[tok * 2 + 0], g1 = g01[tok * 2 + 1];
  const float* r0 = eo + (size_t)s0 * DOUT + lane * 8;
  const float* r1 = eo + (size_t)s1 * DOUT + lane * 8;
  float* o = out + (size_t)tok * DOUT + lane * 8;
  #pragma unroll
  for (int j = 0; j < 2; ++j) {
    float4 v0 = ((const float4*)r0)[j];
    float4 v1 = ((const float4*)r1)[j];
    float4 ov;
    ov.x = g0 * v0.x + g1 * v1.x;
    ov.y = g0 * v0.y + g1 * v1.y;
    ov.z = g0 * v0.z + g1 * v1.z;
    ov.w = g0 * v0.w + g1 * v1.w;
    ((float4*)o)[j] = ov;
  }
}

extern "C" void kernel_launch(void* const* d_in, const int* in_sizes, int n_in,
                              void* d_out, int out_size, void* d_ws, size_t ws_size,
                              hipStream_t stream) {
  const float* x   = (const float*)d_in[0];
  const float* Wr  = (const float*)d_in[1];
  const float* br  = (const float*)d_in[2];
  const float* emb = (const float*)d_in[3];
  const float* W1  = (const float*)d_in[4];
  const float* b1  = (const float*)d_in[5];
  const float* W2  = (const float*)d_in[6];
  const float* b2  = (const float*)d_in[7];
  const float* W3  = (const float*)d_in[8];
  const float* b3  = (const float*)d_in[9];
  float* out = (float*)d_out;
  char* ws = (char*)d_ws;

  float* P      = (float*)(ws + OFF_P);
  float* c      = (float*)(ws + OFF_C);
  int*   counts = (int*)(ws + OFF_CTRL);
  int*   poff   = (int*)(ws + OFF_CTRL + 128);
  int*   e01    = (int*)(ws + OFF_E01);
  float* g01    = (float*)(ws + OFF_G01);
  int*   gtok   = (int*)(ws + OFF_GTOK);
  float* ggate  = (float*)(ws + OFF_GGATE);
  int*   tslot  = (int*)(ws + OFF_TSLOT);
  int*   bhist  = (int*)(ws + OFF_BH);
  int*   bbase  = (int*)(ws + OFF_BB);
  u16*   W1T    = (u16*)(ws + OFF_W1T);
  u16*   W2T    = (u16*)(ws + OFF_W2T);
  u16*   W3T    = (u16*)(ws + OFF_W3T);
  u16*   xbf    = (u16*)(ws + OFF_XBF);
  u16*   h1     = (u16*)(ws + OFF_H1);
  u16*   h2     = (u16*)(ws + OFF_H2);
  float* eo     = (float*)(ws + OFF_EO);

  conv_w<DIN, H1N><<<dim3(H1N / 64, DIN / 64, NE), 256, 0, stream>>>(W1, W1T);
  conv_w<H1N, H2N><<<dim3(H2N / 64, H1N / 64, NE), 256, 0, stream>>>(W2, W2T);
  conv_w<H2N, DOUT><<<dim3(DOUT / 64, H2N / 64, NE), 256, 0, stream>>>(W3, W3T);

  router_prep<<<64, 256, 0, stream>>>(Wr, br, emb, P, c);
  router_score<<<RBLK, 256, 0, stream>>>(x, P, c, e01, g01, bhist, xbf);
  scan_offsets<<<1, 1024, 0, stream>>>(bhist, counts, poff, bbase, gtok);
  build_lists<<<RBLK, 64, 0, stream>>>(e01, g01, bbase, gtok, ggate, tslot);

  int nb1 = (H1N / 128) * MT;
  int nb2 = (H2N / 128) * MT;
  int nb3 = (DOUT / 128) * MT;
  gemm_moe<0, true><<<nb1, 256, 0, stream>>>(xbf, W1T, b1, h1, nullptr,
                                             poff, counts, gtok, nullptr, DIN, H1N, nb1);
  gemm_moe<0, false><<<nb2, 256, 0, stream>>>(h1, W2T, b2, h2, nullptr,
                                              poff, counts, nullptr, nullptr, H1N, H2N, nb2);
  gemm_moe<2, false><<<nb3, 256, 0, stream>>>(h2, W3T, b3, nullptr, eo,
                                              poff, counts, nullptr, nullptr, H2N, DOUT, nb3);
  combine_out<<<N_TOK / 4, 256, 0, stream>>>(eo, tslot, g01, out);
}